// Round 2
// baseline (2340.601 us; speedup 1.0000x reference)
//
#include <hip/hip_runtime.h>
#include <hip/hip_bf16.h>

// GPT2 block fwd: B=2,S=2048,D=1024,H=16,DH=64,F=4096. ALL inputs/output fp32.
// ws layout (floats): h[4096*1024] | q | k | v | ffn_bf16[4096*4096 bf16]
// total 4*16MB + 32MB = 96MB.

#define BDIM 1024
#define SEQ 2048
#define NH 16
#define DHEAD 64
#define FDIM 4096

__device__ __forceinline__ unsigned short f2bf(float f) {
    unsigned int u = __float_as_uint(f);
    unsigned int r = u + 0x7FFFu + ((u >> 16) & 1u);
    return (unsigned short)(r >> 16);
}
__device__ __forceinline__ void bfx2(unsigned int p, float& f0, float& f1) {
    f0 = __uint_as_float(p << 16);
    f1 = __uint_as_float(p & 0xFFFF0000u);
}

// ---------------- LayerNorm: one block per row of 1024 ----------------
__global__ __launch_bounds__(256) void ln_kernel(const float* __restrict__ x,
                                                 const float* __restrict__ g,
                                                 const float* __restrict__ bb,
                                                 float* __restrict__ out) {
    const int D = BDIM;
    const int row = blockIdx.x;
    const int t = threadIdx.x;
    const int c = t * 4;
    float4 p = *(const float4*)(x + (size_t)row * D + c);
    float s = p.x + p.y + p.z + p.w;
    float sq = p.x * p.x + p.y * p.y + p.z * p.z + p.w * p.w;
    for (int off = 1; off < 64; off <<= 1) {
        s += __shfl_xor(s, off);
        sq += __shfl_xor(sq, off);
    }
    __shared__ float ssum[4], ssq[4];
    const int wave = t >> 6, lane = t & 63;
    if (lane == 0) { ssum[wave] = s; ssq[wave] = sq; }
    __syncthreads();
    s = ssum[0] + ssum[1] + ssum[2] + ssum[3];
    sq = ssq[0] + ssq[1] + ssq[2] + ssq[3];
    const float mean = s * (1.0f / BDIM);
    const float var = sq * (1.0f / BDIM) - mean * mean;
    const float rstd = rsqrtf(var + 1e-5f);
    float4 gg = *(const float4*)(g + c);
    float4 bv = *(const float4*)(bb + c);
    float4 o;
    o.x = (p.x - mean) * rstd * gg.x + bv.x;
    o.y = (p.y - mean) * rstd * gg.y + bv.y;
    o.z = (p.z - mean) * rstd * gg.z + bv.z;
    o.w = (p.w - mean) * rstd * gg.w + bv.w;
    *(float4*)(out + (size_t)row * D + c) = o;
}

// ---------------- GEMM: C[M,N] = A[M,K] @ W[K,N] + bias (+res) (gelu?) -------
// 64x64 tile, BK=16, 256 threads, 4x4 micro-tile. A fp32 (or bf16), W/bias/res fp32.
template <int ABF16, int RES, int GELU, int OBF16>
__global__ __launch_bounds__(256) void gemm_kernel(const void* __restrict__ Av,
                                                   const float* __restrict__ W,
                                                   const float* __restrict__ bias,
                                                   const float* __restrict__ resv,
                                                   void* __restrict__ Cv,
                                                   int M, int N, int K) {
    __shared__ float As[16][64];  // [k][m]
    __shared__ float Bs[16][64];  // [k][n]
    const int t = threadIdx.x;
    const int m0 = blockIdx.y * 64, n0 = blockIdx.x * 64;
    const int tx = t & 15, ty = t >> 4;
    const int arow = t >> 2, ak4 = (t & 3) * 4;
    const int brow = t >> 4, bn4 = (t & 15) * 4;
    float acc[4][4] = {};
    for (int k0 = 0; k0 < K; k0 += 16) {
        float a0, a1, a2, a3;
        if (ABF16) {
            const unsigned short* A = (const unsigned short*)Av;
            uint2 p = *(const uint2*)(A + (size_t)(m0 + arow) * K + k0 + ak4);
            bfx2(p.x, a0, a1);
            bfx2(p.y, a2, a3);
        } else {
            const float* A = (const float*)Av;
            float4 p = *(const float4*)(A + (size_t)(m0 + arow) * K + k0 + ak4);
            a0 = p.x; a1 = p.y; a2 = p.z; a3 = p.w;
        }
        float4 wp = *(const float4*)(W + (size_t)(k0 + brow) * N + n0 + bn4);
        __syncthreads();
        As[ak4 + 0][arow] = a0;
        As[ak4 + 1][arow] = a1;
        As[ak4 + 2][arow] = a2;
        As[ak4 + 3][arow] = a3;
        *(float4*)&Bs[brow][bn4] = wp;
        __syncthreads();
#pragma unroll
        for (int kk = 0; kk < 16; ++kk) {
            float4 a = *(const float4*)&As[kk][ty * 4];
            float4 b = *(const float4*)&Bs[kk][tx * 4];
            acc[0][0] += a.x * b.x; acc[0][1] += a.x * b.y; acc[0][2] += a.x * b.z; acc[0][3] += a.x * b.w;
            acc[1][0] += a.y * b.x; acc[1][1] += a.y * b.y; acc[1][2] += a.y * b.z; acc[1][3] += a.y * b.w;
            acc[2][0] += a.z * b.x; acc[2][1] += a.z * b.y; acc[2][2] += a.z * b.z; acc[2][3] += a.z * b.w;
            acc[3][0] += a.w * b.x; acc[3][1] += a.w * b.y; acc[3][2] += a.w * b.z; acc[3][3] += a.w * b.w;
        }
    }
#pragma unroll
    for (int i = 0; i < 4; ++i) {
        const int row = m0 + ty * 4 + i;
#pragma unroll
        for (int j = 0; j < 4; ++j) {
            const int col = n0 + tx * 4 + j;
            float v = acc[i][j] + bias[col];
            if (RES) v += resv[(size_t)row * N + col];
            if (GELU) v = 0.5f * v * (1.0f + erff(v * 0.70710678118654752f));
            if (OBF16)
                ((unsigned short*)Cv)[(size_t)row * N + col] = f2bf(v);
            else
                ((float*)Cv)[(size_t)row * N + col] = v;
        }
    }
}

// ---------------- Flash attention (causal), fp32 in/out ----------------
// Block: 256 thr, 32 queries; key tiles of 32. q/k/v/o layout [B*S, D], head h at col h*64.
__global__ __launch_bounds__(256) void attn_kernel(const float* __restrict__ q,
                                                   const float* __restrict__ k,
                                                   const float* __restrict__ v,
                                                   float* __restrict__ o) {
    const int b = blockIdx.z, h = blockIdx.y;
    const int q0 = blockIdx.x * 32;
    const int t = threadIdx.x;
    const int r = t >> 3;          // 0..31  query row in tile
    const int g8 = t & 7;
    const int d0 = g8 * 8;         // dim slice for loads / PV
    const int c0 = g8 * 4;         // score cols slice

    __shared__ float QsT[64][36];  // [d][r]
    __shared__ float KsT[64][36];  // [d][c]
    __shared__ float Vs[32][68];   // [c][d]
    __shared__ float Ps[32][33];   // [r][c]

    const size_t base = ((size_t)b * SEQ) * BDIM + (size_t)h * DHEAD;

    {
        const float* qrow = q + base + (size_t)(q0 + r) * BDIM + d0;
        float4 qa = *(const float4*)qrow;
        float4 qb = *(const float4*)(qrow + 4);
        QsT[d0 + 0][r] = qa.x * 0.125f;
        QsT[d0 + 1][r] = qa.y * 0.125f;
        QsT[d0 + 2][r] = qa.z * 0.125f;
        QsT[d0 + 3][r] = qa.w * 0.125f;
        QsT[d0 + 4][r] = qb.x * 0.125f;
        QsT[d0 + 5][r] = qb.y * 0.125f;
        QsT[d0 + 6][r] = qb.z * 0.125f;
        QsT[d0 + 7][r] = qb.w * 0.125f;
    }

    float m_r = -INFINITY, l_r = 0.0f;
    float ov[8] = {0, 0, 0, 0, 0, 0, 0, 0};
    const int ntiles = blockIdx.x + 1;
    const int qpos = q0 + r;

    for (int kt = 0; kt < ntiles; ++kt) {
        const int k0 = kt * 32;
        __syncthreads();  // previous tile's Ps/Vs/KsT fully consumed
        {
            const float* krow = k + base + (size_t)(k0 + r) * BDIM + d0;
            float4 ka = *(const float4*)krow;
            float4 kb = *(const float4*)(krow + 4);
            KsT[d0 + 0][r] = ka.x;
            KsT[d0 + 1][r] = ka.y;
            KsT[d0 + 2][r] = ka.z;
            KsT[d0 + 3][r] = ka.w;
            KsT[d0 + 4][r] = kb.x;
            KsT[d0 + 5][r] = kb.y;
            KsT[d0 + 6][r] = kb.z;
            KsT[d0 + 7][r] = kb.w;
            const float* vrow = v + base + (size_t)(k0 + r) * BDIM + d0;
            *(float4*)&Vs[r][d0] = *(const float4*)vrow;
            *(float4*)&Vs[r][d0 + 4] = *(const float4*)(vrow + 4);
        }
        __syncthreads();

        float sc[4] = {0, 0, 0, 0};
#pragma unroll 8
        for (int d = 0; d < 64; ++d) {
            const float qd = QsT[d][r];
            float4 kv = *(const float4*)&KsT[d][c0];
            sc[0] += qd * kv.x;
            sc[1] += qd * kv.y;
            sc[2] += qd * kv.z;
            sc[3] += qd * kv.w;
        }
#pragma unroll
        for (int j = 0; j < 4; ++j)
            if (k0 + c0 + j > qpos) sc[j] = -1e30f;

        float tm = fmaxf(fmaxf(sc[0], sc[1]), fmaxf(sc[2], sc[3]));
        tm = fmaxf(tm, __shfl_xor(tm, 1));
        tm = fmaxf(tm, __shfl_xor(tm, 2));
        tm = fmaxf(tm, __shfl_xor(tm, 4));
        const float newm = fmaxf(m_r, tm);
        const float alpha = __expf(m_r - newm);
        float p[4], psum = 0.0f;
#pragma unroll
        for (int j = 0; j < 4; ++j) {
            p[j] = __expf(sc[j] - newm);
            psum += p[j];
        }
        psum += __shfl_xor(psum, 1);
        psum += __shfl_xor(psum, 2);
        psum += __shfl_xor(psum, 4);
        l_r = l_r * alpha + psum;
        m_r = newm;
        Ps[r][c0 + 0] = p[0];
        Ps[r][c0 + 1] = p[1];
        Ps[r][c0 + 2] = p[2];
        Ps[r][c0 + 3] = p[3];
#pragma unroll
        for (int i = 0; i < 8; ++i) ov[i] *= alpha;
        __syncthreads();
#pragma unroll 4
        for (int c = 0; c < 32; ++c) {
            const float pv = Ps[r][c];
            float4 va = *(const float4*)&Vs[c][d0];
            float4 vb = *(const float4*)&Vs[c][d0 + 4];
            ov[0] += pv * va.x;
            ov[1] += pv * va.y;
            ov[2] += pv * va.z;
            ov[3] += pv * va.w;
            ov[4] += pv * vb.x;
            ov[5] += pv * vb.y;
            ov[6] += pv * vb.z;
            ov[7] += pv * vb.w;
        }
    }
    const float inv = 1.0f / l_r;
    float* orow = o + base + (size_t)(q0 + r) * BDIM + d0;
    *(float4*)orow = make_float4(ov[0] * inv, ov[1] * inv, ov[2] * inv, ov[3] * inv);
    *(float4*)(orow + 4) = make_float4(ov[4] * inv, ov[5] * inv, ov[6] * inv, ov[7] * inv);
}

extern "C" void kernel_launch(void* const* d_in, const int* in_sizes, int n_in,
                              void* d_out, int out_size, void* d_ws, size_t ws_size,
                              hipStream_t stream) {
    const int B = 2, S = SEQ, D = BDIM, F = FDIM;
    const int M = B * S;  // 4096

    const float* x = (const float*)d_in[0];
    const float* ln1_g = (const float*)d_in[1];
    const float* ln1_b = (const float*)d_in[2];
    const float* wq = (const float*)d_in[3];
    const float* bq = (const float*)d_in[4];
    const float* wk = (const float*)d_in[5];
    const float* bk = (const float*)d_in[6];
    const float* wv = (const float*)d_in[7];
    const float* bv = (const float*)d_in[8];
    const float* wo = (const float*)d_in[9];
    const float* bo = (const float*)d_in[10];
    const float* ln2_g = (const float*)d_in[11];
    const float* ln2_b = (const float*)d_in[12];
    const float* w1 = (const float*)d_in[13];
    const float* b1 = (const float*)d_in[14];
    const float* w2 = (const float*)d_in[15];
    const float* b2 = (const float*)d_in[16];

    float* ws = (float*)d_ws;
    float* hbuf = ws;                            // h, then attention output o
    float* qb = ws + (size_t)M * D;              // q, then add1
    float* kb = ws + (size_t)2 * M * D;          // k
    float* vb = ws + (size_t)3 * M * D;          // v, then h2
    unsigned short* ffn = (unsigned short*)(ws + (size_t)4 * M * D);  // [M,F] bf16

    // 1. h = LN1(x)
    ln_kernel<<<M, 256, 0, stream>>>(x, ln1_g, ln1_b, hbuf);

    // 2. q,k,v = h @ w{q,k,v} + b
    dim3 g1(D / 64, M / 64);
    gemm_kernel<0, 0, 0, 0><<<g1, 256, 0, stream>>>(hbuf, wq, bq, nullptr, qb, M, D, D);
    gemm_kernel<0, 0, 0, 0><<<g1, 256, 0, stream>>>(hbuf, wk, bk, nullptr, kb, M, D, D);
    gemm_kernel<0, 0, 0, 0><<<g1, 256, 0, stream>>>(hbuf, wv, bv, nullptr, vb, M, D, D);

    // 3. o = causal_attention(q,k,v)  -> hbuf
    dim3 ga(S / 32, NH, B);
    attn_kernel<<<ga, 256, 0, stream>>>(qb, kb, vb, hbuf);

    // 4. add1 = o @ wo + bo + x  -> qb
    gemm_kernel<0, 1, 0, 0><<<g1, 256, 0, stream>>>(hbuf, wo, bo, x, qb, M, D, D);

    // 5. h2 = LN2(add1) -> vb
    ln_kernel<<<M, 256, 0, stream>>>(qb, ln2_g, ln2_b, vb);

    // 6. ffn = gelu(h2 @ w1 + b1) -> bf16
    dim3 g2(F / 64, M / 64);
    gemm_kernel<0, 0, 1, 1><<<g2, 256, 0, stream>>>(vb, w1, b1, nullptr, ffn, M, F, D);

    // 7. out = ffn @ w2 + b2 + add1 -> fp32 d_out
    dim3 g3(D / 64, M / 64);
    gemm_kernel<1, 1, 0, 0><<<g3, 256, 0, stream>>>(ffn, w2, b2, qb, d_out, M, D, F);
}

// Round 3
// 1166.088 us; speedup vs baseline: 2.0072x; 2.0072x over previous
//
#include <hip/hip_runtime.h>
#include <hip/hip_bf16.h>

// GPT2 block fwd: B=2,S=2048,D=1024,H=16,DH=64,F=4096. fp32 in/out, bf16 MFMA GEMMs.
// ws layout (bytes):
//   [0,24M)  qkv bf16 [4096][3072]   (region reused by ffn [4096][4096] bf16, 32MB)
//   [32M,40M) hbuf bf16: h (LN1 out), later attention output o
//   [40M,56M) add1 fp32 [4096][1024]
//   [56M,64M) h2 bf16
//   [64M,70M) qkvT bf16 [3072][1024]  (wq^T | wk^T | wv^T)
//   [70M,72M) woT bf16 [1024][1024]
//   [72M,80M) w1T bf16 [4096][1024]
//   [80M,88M) w2T bf16 [1024][4096]
//   [88M,..) bias_qkv fp32 [3072]
// total ~88MB.

#define BDIM 1024
#define SEQ 2048
#define NH 16
#define DHEAD 64
#define FDIM 4096
#define QKVD 3072

typedef __attribute__((ext_vector_type(8))) short short8v;
typedef __attribute__((ext_vector_type(4))) float floatx4;

__device__ __forceinline__ unsigned short f2bf(float f) {
    unsigned int u = __float_as_uint(f);
    unsigned int r = u + 0x7FFFu + ((u >> 16) & 1u);
    return (unsigned short)(r >> 16);
}
__device__ __forceinline__ void bfx2(unsigned int p, float& f0, float& f1) {
    f0 = __uint_as_float(p << 16);
    f1 = __uint_as_float(p & 0xFFFF0000u);
}

__device__ __forceinline__ void load16_lds(const unsigned short* g, short* l) {
    __builtin_amdgcn_global_load_lds((const __attribute__((address_space(1))) void*)g,
                                     (__attribute__((address_space(3))) void*)l, 16, 0, 0);
}

// ---------------- weight fp32 [K,N] -> bf16 [N,K] transpose ----------------
__global__ __launch_bounds__(256) void transpose_bf16(const float* __restrict__ W,
                                                      unsigned short* __restrict__ Wt,
                                                      int K, int N) {
    __shared__ float tile[32][33];
    const int t = threadIdx.x;
    const int r = t >> 3, c4 = (t & 7) * 4;
    const int n0 = blockIdx.x * 32, k0 = blockIdx.y * 32;
    float4 p = *(const float4*)(W + (size_t)(k0 + r) * N + n0 + c4);
    tile[r][c4 + 0] = p.x;
    tile[r][c4 + 1] = p.y;
    tile[r][c4 + 2] = p.z;
    tile[r][c4 + 3] = p.w;
    __syncthreads();
    ushort4 ou;
    ou.x = f2bf(tile[c4 + 0][r]);
    ou.y = f2bf(tile[c4 + 1][r]);
    ou.z = f2bf(tile[c4 + 2][r]);
    ou.w = f2bf(tile[c4 + 3][r]);
    *(ushort4*)(Wt + (size_t)(n0 + r) * K + k0 + c4) = ou;
}

__global__ void concat_bias(const float* __restrict__ a, const float* __restrict__ b,
                            const float* __restrict__ c, float* __restrict__ out) {
    int i = blockIdx.x * 256 + threadIdx.x;
    out[i] = (i < 1024) ? a[i] : (i < 2048 ? b[i - 1024] : c[i - 2048]);
}

// ---------------- LayerNorm: fp32 in -> bf16 out ----------------
__global__ __launch_bounds__(256) void ln_kernel(const float* __restrict__ x,
                                                 const float* __restrict__ g,
                                                 const float* __restrict__ bb,
                                                 unsigned short* __restrict__ out) {
    const int row = blockIdx.x;
    const int t = threadIdx.x;
    const int c = t * 4;
    float4 p = *(const float4*)(x + (size_t)row * BDIM + c);
    float s = p.x + p.y + p.z + p.w;
    float sq = p.x * p.x + p.y * p.y + p.z * p.z + p.w * p.w;
    for (int off = 1; off < 64; off <<= 1) {
        s += __shfl_xor(s, off);
        sq += __shfl_xor(sq, off);
    }
    __shared__ float ssum[4], ssq[4];
    const int wave = t >> 6, lane = t & 63;
    if (lane == 0) { ssum[wave] = s; ssq[wave] = sq; }
    __syncthreads();
    s = ssum[0] + ssum[1] + ssum[2] + ssum[3];
    sq = ssq[0] + ssq[1] + ssq[2] + ssq[3];
    const float mean = s * (1.0f / BDIM);
    const float var = sq * (1.0f / BDIM) - mean * mean;
    const float rstd = rsqrtf(var + 1e-5f);
    float4 gg = *(const float4*)(g + c);
    float4 bv = *(const float4*)(bb + c);
    ushort4 o;
    o.x = f2bf((p.x - mean) * rstd * gg.x + bv.x);
    o.y = f2bf((p.y - mean) * rstd * gg.y + bv.y);
    o.z = f2bf((p.z - mean) * rstd * gg.z + bv.z);
    o.w = f2bf((p.w - mean) * rstd * gg.w + bv.w);
    *(ushort4*)(out + (size_t)row * BDIM + c) = o;
}

// ---------------- MFMA GEMM: C[M,N] = A[M,K](bf16) @ Bt[N,K]^T(bf16) + bias ----
// 128xBN tile, BK=32, 256 thr = 4 waves. BN=128: wave 64x64, acc 4x4. BN=64: wave 32x64, acc 2x4.
template <int BN, int RES, int GELU, int OBF16>
__global__ __launch_bounds__(256) void mfma_gemm(const unsigned short* __restrict__ A,
                                                 const unsigned short* __restrict__ Bt,
                                                 const float* __restrict__ bias,
                                                 const float* __restrict__ res,
                                                 void* __restrict__ Cv,
                                                 int M, int N, int K) {
    constexpr int MI = (BN == 128) ? 4 : 2;
    __shared__ short As[128 * 32];
    __shared__ short Bs[BN * 32];
    const int t = threadIdx.x;
    const int wave = t >> 6, lane = t & 63;
    const int m0 = blockIdx.y * 128, n0 = blockIdx.x * BN;
    const int wmrow = (BN == 128) ? (wave & 1) * 64 : wave * 32;
    const int wnrow = (BN == 128) ? (wave >> 1) * 64 : 0;
    const int mlane = lane & 15, quad = lane >> 4;

    floatx4 acc[MI][4];
#pragma unroll
    for (int mi = 0; mi < MI; ++mi)
#pragma unroll
        for (int ni = 0; ni < 4; ++ni) {
            floatx4 z = {0.0f, 0.0f, 0.0f, 0.0f};
            acc[mi][ni] = z;
        }

    for (int k0 = 0; k0 < K; k0 += 32) {
        __syncthreads();
        // stage A tile 128x32 (512 16B-chunks, 2 per thread), row-major [m][k]
#pragma unroll
        for (int j = 0; j < 2; ++j) {
            const int c = j * 256 + wave * 64 + lane;
            load16_lds(A + (size_t)(m0 + (c >> 2)) * K + k0 + (c & 3) * 8, &As[c * 8]);
        }
        // stage Bt tile BNx32, row-major [n][k]
#pragma unroll
        for (int j = 0; j < BN / 64; ++j) {
            const int c = j * 256 + wave * 64 + lane;
            load16_lds(Bt + (size_t)(n0 + (c >> 2)) * K + k0 + (c & 3) * 8, &Bs[c * 8]);
        }
        __syncthreads();
        short8v a[MI], b[4];
#pragma unroll
        for (int mi = 0; mi < MI; ++mi)
            a[mi] = *(const short8v*)&As[(wmrow + mi * 16 + mlane) * 32 + quad * 8];
#pragma unroll
        for (int ni = 0; ni < 4; ++ni)
            b[ni] = *(const short8v*)&Bs[(wnrow + ni * 16 + mlane) * 32 + quad * 8];
#pragma unroll
        for (int mi = 0; mi < MI; ++mi)
#pragma unroll
            for (int ni = 0; ni < 4; ++ni)
                acc[mi][ni] = __builtin_amdgcn_mfma_f32_16x16x32_bf16(a[mi], b[ni], acc[mi][ni], 0, 0, 0);
    }
    // epilogue: D[row=quad*4+reg][col=lane&15]
#pragma unroll
    for (int mi = 0; mi < MI; ++mi) {
#pragma unroll
        for (int ni = 0; ni < 4; ++ni) {
            const int col = n0 + wnrow + ni * 16 + mlane;
            const float bv = bias[col];
#pragma unroll
            for (int rg = 0; rg < 4; ++rg) {
                const int row = m0 + wmrow + mi * 16 + quad * 4 + rg;
                float v = acc[mi][ni][rg] + bv;
                if (RES) v += res[(size_t)row * N + col];
                if (GELU) v = 0.5f * v * (1.0f + erff(v * 0.70710678118654752f));
                if (OBF16)
                    ((unsigned short*)Cv)[(size_t)row * N + col] = f2bf(v);
                else
                    ((float*)Cv)[(size_t)row * N + col] = v;
            }
        }
    }
}

// ---------------- Flash attention (causal), bf16 in/out, fp32 LDS ----------------
// qkv [B*S][3072]: q cols 0..1023, k 1024.., v 2048.., head h at +h*64. o [B*S][1024].
__global__ __launch_bounds__(256) void attn_kernel(const unsigned short* __restrict__ qkv,
                                                   unsigned short* __restrict__ o) {
    const int b = blockIdx.z, h = blockIdx.y;
    const int q0 = blockIdx.x * 32;
    const int t = threadIdx.x;
    const int r = t >> 3;
    const int g8 = t & 7;
    const int d0 = g8 * 8;
    const int c0 = g8 * 4;

    __shared__ float QsT[64][33];  // [d][r]  stride 33: writes 2-way, reads conflict-free
    __shared__ float KsT[64][33];  // [d][c]
    __shared__ float Vs[32][68];   // [c][d]
    __shared__ float Ps[32][33];   // [r][c]

    const unsigned short* qbase = qkv + (size_t)b * SEQ * QKVD + (size_t)h * DHEAD;

    {
        uint4 p = *(const uint4*)(qbase + (size_t)(q0 + r) * QKVD + d0);
        float f0, f1, f2, f3, f4, f5, f6, f7;
        bfx2(p.x, f0, f1); bfx2(p.y, f2, f3); bfx2(p.z, f4, f5); bfx2(p.w, f6, f7);
        QsT[d0 + 0][r] = f0 * 0.125f;
        QsT[d0 + 1][r] = f1 * 0.125f;
        QsT[d0 + 2][r] = f2 * 0.125f;
        QsT[d0 + 3][r] = f3 * 0.125f;
        QsT[d0 + 4][r] = f4 * 0.125f;
        QsT[d0 + 5][r] = f5 * 0.125f;
        QsT[d0 + 6][r] = f6 * 0.125f;
        QsT[d0 + 7][r] = f7 * 0.125f;
    }

    float m_r = -INFINITY, l_r = 0.0f;
    float ov[8] = {0, 0, 0, 0, 0, 0, 0, 0};
    const int ntiles = blockIdx.x + 1;
    const int qpos = q0 + r;

    for (int kt = 0; kt < ntiles; ++kt) {
        const int k0 = kt * 32;
        __syncthreads();
        {
            uint4 p = *(const uint4*)(qbase + 1024 + (size_t)(k0 + r) * QKVD + d0);
            float f0, f1, f2, f3, f4, f5, f6, f7;
            bfx2(p.x, f0, f1); bfx2(p.y, f2, f3); bfx2(p.z, f4, f5); bfx2(p.w, f6, f7);
            KsT[d0 + 0][r] = f0;
            KsT[d0 + 1][r] = f1;
            KsT[d0 + 2][r] = f2;
            KsT[d0 + 3][r] = f3;
            KsT[d0 + 4][r] = f4;
            KsT[d0 + 5][r] = f5;
            KsT[d0 + 6][r] = f6;
            KsT[d0 + 7][r] = f7;
            uint4 pv = *(const uint4*)(qbase + 2048 + (size_t)(k0 + r) * QKVD + d0);
            float v0, v1, v2, v3, v4, v5, v6, v7;
            bfx2(pv.x, v0, v1); bfx2(pv.y, v2, v3); bfx2(pv.z, v4, v5); bfx2(pv.w, v6, v7);
            *(float4*)&Vs[r][d0] = make_float4(v0, v1, v2, v3);
            *(float4*)&Vs[r][d0 + 4] = make_float4(v4, v5, v6, v7);
        }
        __syncthreads();

        float sc[4] = {0, 0, 0, 0};
#pragma unroll 8
        for (int d = 0; d < 64; ++d) {
            const float qd = QsT[d][r];
            sc[0] += qd * KsT[d][c0 + 0];
            sc[1] += qd * KsT[d][c0 + 1];
            sc[2] += qd * KsT[d][c0 + 2];
            sc[3] += qd * KsT[d][c0 + 3];
        }
#pragma unroll
        for (int j = 0; j < 4; ++j)
            if (k0 + c0 + j > qpos) sc[j] = -1e30f;

        float tm = fmaxf(fmaxf(sc[0], sc[1]), fmaxf(sc[2], sc[3]));
        tm = fmaxf(tm, __shfl_xor(tm, 1));
        tm = fmaxf(tm, __shfl_xor(tm, 2));
        tm = fmaxf(tm, __shfl_xor(tm, 4));
        const float newm = fmaxf(m_r, tm);
        const float alpha = __expf(m_r - newm);
        float p[4], psum = 0.0f;
#pragma unroll
        for (int j = 0; j < 4; ++j) {
            p[j] = __expf(sc[j] - newm);
            psum += p[j];
        }
        psum += __shfl_xor(psum, 1);
        psum += __shfl_xor(psum, 2);
        psum += __shfl_xor(psum, 4);
        l_r = l_r * alpha + psum;
        m_r = newm;
        Ps[r][c0 + 0] = p[0];
        Ps[r][c0 + 1] = p[1];
        Ps[r][c0 + 2] = p[2];
        Ps[r][c0 + 3] = p[3];
#pragma unroll
        for (int i = 0; i < 8; ++i) ov[i] *= alpha;
        __syncthreads();
#pragma unroll 4
        for (int c = 0; c < 32; ++c) {
            const float pv = Ps[r][c];
            float4 va = *(const float4*)&Vs[c][d0];
            float4 vb = *(const float4*)&Vs[c][d0 + 4];
            ov[0] += pv * va.x;
            ov[1] += pv * va.y;
            ov[2] += pv * va.z;
            ov[3] += pv * va.w;
            ov[4] += pv * vb.x;
            ov[5] += pv * vb.y;
            ov[6] += pv * vb.z;
            ov[7] += pv * vb.w;
        }
    }
    const float inv = 1.0f / l_r;
    unsigned short* orow = o + ((size_t)b * SEQ + q0 + r) * BDIM + h * DHEAD + d0;
    uint4 pk;
    pk.x = (unsigned int)f2bf(ov[0] * inv) | ((unsigned int)f2bf(ov[1] * inv) << 16);
    pk.y = (unsigned int)f2bf(ov[2] * inv) | ((unsigned int)f2bf(ov[3] * inv) << 16);
    pk.z = (unsigned int)f2bf(ov[4] * inv) | ((unsigned int)f2bf(ov[5] * inv) << 16);
    pk.w = (unsigned int)f2bf(ov[6] * inv) | ((unsigned int)f2bf(ov[7] * inv) << 16);
    *(uint4*)orow = pk;
}

extern "C" void kernel_launch(void* const* d_in, const int* in_sizes, int n_in,
                              void* d_out, int out_size, void* d_ws, size_t ws_size,
                              hipStream_t stream) {
    const int M = 2 * SEQ;  // 4096

    const float* x = (const float*)d_in[0];
    const float* ln1_g = (const float*)d_in[1];
    const float* ln1_b = (const float*)d_in[2];
    const float* wq = (const float*)d_in[3];
    const float* bq = (const float*)d_in[4];
    const float* wk = (const float*)d_in[5];
    const float* bk = (const float*)d_in[6];
    const float* wv = (const float*)d_in[7];
    const float* bv = (const float*)d_in[8];
    const float* wo = (const float*)d_in[9];
    const float* bo = (const float*)d_in[10];
    const float* ln2_g = (const float*)d_in[11];
    const float* ln2_b = (const float*)d_in[12];
    const float* w1 = (const float*)d_in[13];
    const float* b1 = (const float*)d_in[14];
    const float* w2 = (const float*)d_in[15];
    const float* b2 = (const float*)d_in[16];

    char* wsb = (char*)d_ws;
    unsigned short* qkv = (unsigned short*)wsb;                    // [M][3072], reused by ffn
    unsigned short* ffn = (unsigned short*)wsb;                    // [M][4096]
    unsigned short* hbuf = (unsigned short*)(wsb + (32u << 20));   // h then o
    float* add1 = (float*)(wsb + (40u << 20));
    unsigned short* h2 = (unsigned short*)(wsb + (56u << 20));
    unsigned short* qkvT = (unsigned short*)(wsb + (64u << 20));   // [3072][1024]
    unsigned short* woT = (unsigned short*)(wsb + (70u << 20));    // [1024][1024]
    unsigned short* w1T = (unsigned short*)(wsb + (72u << 20));    // [4096][1024]
    unsigned short* w2T = (unsigned short*)(wsb + (80u << 20));    // [1024][4096]
    float* bqkv = (float*)(wsb + (88u << 20));                     // [3072]

    // 0. weight convert+transpose, bias concat
    transpose_bf16<<<dim3(32, 32), 256, 0, stream>>>(wq, qkvT, 1024, 1024);
    transpose_bf16<<<dim3(32, 32), 256, 0, stream>>>(wk, qkvT + 1024 * 1024, 1024, 1024);
    transpose_bf16<<<dim3(32, 32), 256, 0, stream>>>(wv, qkvT + 2048 * 1024, 1024, 1024);
    transpose_bf16<<<dim3(32, 32), 256, 0, stream>>>(wo, woT, 1024, 1024);
    transpose_bf16<<<dim3(128, 32), 256, 0, stream>>>(w1, w1T, 1024, 4096);
    transpose_bf16<<<dim3(32, 128), 256, 0, stream>>>(w2, w2T, 4096, 1024);
    concat_bias<<<12, 256, 0, stream>>>(bq, bk, bv, bqkv);

    // 1. h = LN1(x) -> bf16
    ln_kernel<<<M, 256, 0, stream>>>(x, ln1_g, ln1_b, hbuf);

    // 2. qkv = h @ [wq|wk|wv] + [bq|bk|bv]   (M=4096, N=3072, K=1024)
    mfma_gemm<128, 0, 0, 1><<<dim3(QKVD / 128, M / 128), 256, 0, stream>>>(
        hbuf, qkvT, bqkv, nullptr, qkv, M, QKVD, 1024);

    // 3. o = causal_attention(qkv) -> hbuf (h dead)
    attn_kernel<<<dim3(SEQ / 32, NH, 2), 256, 0, stream>>>(qkv, hbuf);

    // 4. add1 = o @ wo + bo + x (fp32)
    mfma_gemm<64, 1, 0, 0><<<dim3(1024 / 64, M / 128), 256, 0, stream>>>(
        hbuf, woT, bo, x, add1, M, 1024, 1024);

    // 5. h2 = LN2(add1) -> bf16
    ln_kernel<<<M, 256, 0, stream>>>(add1, ln2_g, ln2_b, h2);

    // 6. ffn = gelu(h2 @ w1 + b1) -> bf16 (overwrites qkv region; qkv dead)
    mfma_gemm<128, 0, 1, 1><<<dim3(FDIM / 128, M / 128), 256, 0, stream>>>(
        h2, w1T, b1, nullptr, ffn, M, FDIM, 1024);

    // 7. out = ffn @ w2 + b2 + add1 -> fp32 d_out  (K=4096)
    mfma_gemm<64, 1, 0, 0><<<dim3(1024 / 64, M / 128), 256, 0, stream>>>(
        ffn, w2T, b2, add1, (float*)d_out, M, 1024, FDIM);
}

// Round 4
// 583.529 us; speedup vs baseline: 4.0111x; 1.9983x over previous
//
#include <hip/hip_runtime.h>
#include <hip/hip_bf16.h>

// GPT2 block fwd: B=2,S=2048,D=1024,H=16,DH=64,F=4096. fp32 in/out, bf16 MFMA.
// ws layout (bytes):
//   [0,24M)   qkv bf16 [4096][3072]   (slot reused by ffn [4096][4096] bf16 = 32MB)
//   [24M,32M) vt bf16 [32 bh][64 d][2048 s]  (live only between QKV gemm and attn)
//   [32M,40M) hbuf bf16: h (LN1 out), later attention output o
//   [40M,56M) add1 fp32 [4096][1024]
//   [56M,64M) h2 bf16
//   [64M,70M) qkvT bf16 | [70M,72M) woT | [72M,80M) w1T | [80M,88M) w2T
//   [88M,..)  bias_qkv fp32 [3072]
// total ~88MB.

#define BDIM 1024
#define SEQ 2048
#define NH 16
#define DHEAD 64
#define FDIM 4096
#define QKVD 3072

typedef __attribute__((ext_vector_type(8))) short short8v;
typedef __attribute__((ext_vector_type(4))) float floatx4;

__device__ __forceinline__ unsigned short f2bf(float f) {
    unsigned int u = __float_as_uint(f);
    unsigned int r = u + 0x7FFFu + ((u >> 16) & 1u);
    return (unsigned short)(r >> 16);
}

__device__ __forceinline__ void load16_lds(const unsigned short* g, short* l) {
    __builtin_amdgcn_global_load_lds((const __attribute__((address_space(1))) void*)g,
                                     (__attribute__((address_space(3))) void*)l, 16, 0, 0);
}

// ---------------- weight fp32 [K,N] -> bf16 [N,K] transpose ----------------
__global__ __launch_bounds__(256) void transpose_bf16(const float* __restrict__ W,
                                                      unsigned short* __restrict__ Wt,
                                                      int K, int N) {
    __shared__ float tile[32][33];
    const int t = threadIdx.x;
    const int r = t >> 3, c4 = (t & 7) * 4;
    const int n0 = blockIdx.x * 32, k0 = blockIdx.y * 32;
    float4 p = *(const float4*)(W + (size_t)(k0 + r) * N + n0 + c4);
    tile[r][c4 + 0] = p.x;
    tile[r][c4 + 1] = p.y;
    tile[r][c4 + 2] = p.z;
    tile[r][c4 + 3] = p.w;
    __syncthreads();
    ushort4 ou;
    ou.x = f2bf(tile[c4 + 0][r]);
    ou.y = f2bf(tile[c4 + 1][r]);
    ou.z = f2bf(tile[c4 + 2][r]);
    ou.w = f2bf(tile[c4 + 3][r]);
    *(ushort4*)(Wt + (size_t)(n0 + r) * K + k0 + c4) = ou;
}

__global__ void concat_bias(const float* __restrict__ a, const float* __restrict__ b,
                            const float* __restrict__ c, float* __restrict__ out) {
    int i = blockIdx.x * 256 + threadIdx.x;
    out[i] = (i < 1024) ? a[i] : (i < 2048 ? b[i - 1024] : c[i - 2048]);
}

// ---------------- V transpose: qkv V-cols -> vt[bh][d][s] ----------------
__global__ __launch_bounds__(256) void transpose_v(const unsigned short* __restrict__ qkv,
                                                   unsigned short* __restrict__ vt) {
    const int bh = blockIdx.y;
    const int b = bh >> 4, h = bh & 15;
    const int s0 = blockIdx.x * 64;
    __shared__ unsigned short tile[64][80];  // 80: keeps 16B alignment of rows
    const int t = threadIdx.x;
#pragma unroll
    for (int j = 0; j < 2; ++j) {
        const int c = j * 256 + t;
        const int s = c >> 3, d8 = (c & 7) * 8;
        uint4 p = *(const uint4*)(qkv + (size_t)(b * SEQ + s0 + s) * QKVD + 2048 + h * 64 + d8);
        *(uint4*)&tile[s][d8] = p;
    }
    __syncthreads();
#pragma unroll
    for (int j = 0; j < 2; ++j) {
        const int c = j * 256 + t;
        const int d = c >> 3, s8 = (c & 7) * 8;
        unsigned int w0 = (unsigned int)tile[s8 + 0][d] | ((unsigned int)tile[s8 + 1][d] << 16);
        unsigned int w1 = (unsigned int)tile[s8 + 2][d] | ((unsigned int)tile[s8 + 3][d] << 16);
        unsigned int w2 = (unsigned int)tile[s8 + 4][d] | ((unsigned int)tile[s8 + 5][d] << 16);
        unsigned int w3 = (unsigned int)tile[s8 + 6][d] | ((unsigned int)tile[s8 + 7][d] << 16);
        uint4 o = {w0, w1, w2, w3};
        *(uint4*)(vt + ((size_t)bh * 64 + d) * SEQ + s0 + s8) = o;
    }
}

// ---------------- LayerNorm: fp32 in -> bf16 out ----------------
__global__ __launch_bounds__(256) void ln_kernel(const float* __restrict__ x,
                                                 const float* __restrict__ g,
                                                 const float* __restrict__ bb,
                                                 unsigned short* __restrict__ out) {
    const int row = blockIdx.x;
    const int t = threadIdx.x;
    const int c = t * 4;
    float4 p = *(const float4*)(x + (size_t)row * BDIM + c);
    float s = p.x + p.y + p.z + p.w;
    float sq = p.x * p.x + p.y * p.y + p.z * p.z + p.w * p.w;
    for (int off = 1; off < 64; off <<= 1) {
        s += __shfl_xor(s, off);
        sq += __shfl_xor(sq, off);
    }
    __shared__ float ssum[4], ssq[4];
    const int wave = t >> 6, lane = t & 63;
    if (lane == 0) { ssum[wave] = s; ssq[wave] = sq; }
    __syncthreads();
    s = ssum[0] + ssum[1] + ssum[2] + ssum[3];
    sq = ssq[0] + ssq[1] + ssq[2] + ssq[3];
    const float mean = s * (1.0f / BDIM);
    const float var = sq * (1.0f / BDIM) - mean * mean;
    const float rstd = rsqrtf(var + 1e-5f);
    float4 gg = *(const float4*)(g + c);
    float4 bv = *(const float4*)(bb + c);
    ushort4 o;
    o.x = f2bf((p.x - mean) * rstd * gg.x + bv.x);
    o.y = f2bf((p.y - mean) * rstd * gg.y + bv.y);
    o.z = f2bf((p.z - mean) * rstd * gg.z + bv.z);
    o.w = f2bf((p.w - mean) * rstd * gg.w + bv.w);
    *(ushort4*)(out + (size_t)row * BDIM + c) = o;
}

// ---------------- MFMA GEMM (as round 3) ----------------
template <int BN, int RES, int GELU, int OBF16>
__global__ __launch_bounds__(256) void mfma_gemm(const unsigned short* __restrict__ A,
                                                 const unsigned short* __restrict__ Bt,
                                                 const float* __restrict__ bias,
                                                 const float* __restrict__ res,
                                                 void* __restrict__ Cv,
                                                 int M, int N, int K) {
    constexpr int MI = (BN == 128) ? 4 : 2;
    __shared__ short As[128 * 32];
    __shared__ short Bs[BN * 32];
    const int t = threadIdx.x;
    const int wave = t >> 6, lane = t & 63;
    const int m0 = blockIdx.y * 128, n0 = blockIdx.x * BN;
    const int wmrow = (BN == 128) ? (wave & 1) * 64 : wave * 32;
    const int wnrow = (BN == 128) ? (wave >> 1) * 64 : 0;
    const int mlane = lane & 15, quad = lane >> 4;

    floatx4 acc[MI][4];
#pragma unroll
    for (int mi = 0; mi < MI; ++mi)
#pragma unroll
        for (int ni = 0; ni < 4; ++ni) {
            floatx4 z = {0.0f, 0.0f, 0.0f, 0.0f};
            acc[mi][ni] = z;
        }

    for (int k0 = 0; k0 < K; k0 += 32) {
        __syncthreads();
#pragma unroll
        for (int j = 0; j < 2; ++j) {
            const int c = j * 256 + wave * 64 + lane;
            load16_lds(A + (size_t)(m0 + (c >> 2)) * K + k0 + (c & 3) * 8, &As[c * 8]);
        }
#pragma unroll
        for (int j = 0; j < BN / 64; ++j) {
            const int c = j * 256 + wave * 64 + lane;
            load16_lds(Bt + (size_t)(n0 + (c >> 2)) * K + k0 + (c & 3) * 8, &Bs[c * 8]);
        }
        __syncthreads();
        short8v a[MI], b[4];
#pragma unroll
        for (int mi = 0; mi < MI; ++mi)
            a[mi] = *(const short8v*)&As[(wmrow + mi * 16 + mlane) * 32 + quad * 8];
#pragma unroll
        for (int ni = 0; ni < 4; ++ni)
            b[ni] = *(const short8v*)&Bs[(wnrow + ni * 16 + mlane) * 32 + quad * 8];
#pragma unroll
        for (int mi = 0; mi < MI; ++mi)
#pragma unroll
            for (int ni = 0; ni < 4; ++ni)
                acc[mi][ni] = __builtin_amdgcn_mfma_f32_16x16x32_bf16(a[mi], b[ni], acc[mi][ni], 0, 0, 0);
    }
#pragma unroll
    for (int mi = 0; mi < MI; ++mi) {
#pragma unroll
        for (int ni = 0; ni < 4; ++ni) {
            const int col = n0 + wnrow + ni * 16 + mlane;
            const float bv = bias[col];
#pragma unroll
            for (int rg = 0; rg < 4; ++rg) {
                const int row = m0 + wmrow + mi * 16 + quad * 4 + rg;
                float v = acc[mi][ni][rg] + bv;
                if (RES) v += res[(size_t)row * N + col];
                if (GELU) v = 0.5f * v * (1.0f + erff(v * 0.70710678118654752f));
                if (OBF16)
                    ((unsigned short*)Cv)[(size_t)row * N + col] = f2bf(v);
                else
                    ((float*)Cv)[(size_t)row * N + col] = v;
            }
        }
    }
}

// ---------------- MFMA flash attention (causal), barrier-free, LDS-free -----
// S^T = K·Q^T via mfma(16x16x32): C col = query(lane&15), row = key(quad*4+reg).
// Softmax state m,l = one scalar per lane. O^T = V^T·P^T, V^T from vt.
// 4 waves/block, each wave owns 16 queries, iterates 32-key windows.
__global__ __launch_bounds__(256) void attn_kernel(const unsigned short* __restrict__ qkv,
                                                   const unsigned short* __restrict__ vt,
                                                   unsigned short* __restrict__ o) {
    const int b = blockIdx.z, h = blockIdx.y;
    const int qt = gridDim.x - 1 - blockIdx.x;  // big blocks first
    const int wave = threadIdx.x >> 6, lane = threadIdx.x & 63;
    const int mlane = lane & 15, quad = lane >> 4;
    const int wq0 = qt * 64 + wave * 16;        // first query of this wave
    const size_t bS = (size_t)b * SEQ;

    // Q fragments (B-operand): B[k=dim][n=query], held for the whole wave.
    const unsigned short* qrow = qkv + (bS + wq0 + mlane) * QKVD + h * DHEAD;
    short8v qf0 = *(const short8v*)(qrow + quad * 8);
    short8v qf1 = *(const short8v*)(qrow + 32 + quad * 8);

    const unsigned short* kbase = qkv + bS * QKVD + 1024 + h * DHEAD;
    const unsigned short* vbase = vt + ((size_t)(b * NH + h)) * DHEAD * SEQ;

    floatx4 ot[4];
#pragma unroll
    for (int mt = 0; mt < 4; ++mt) { floatx4 z = {0, 0, 0, 0}; ot[mt] = z; }
    float m_r = -INFINITY, l_r = 0.0f;

    const int kend = wq0 + 16;
    const int klast = ((kend - 1) >> 5) << 5;
    const int myq = wq0 + mlane;

    for (int k0 = 0; k0 < kend; k0 += 32) {
        // ---- K fragments (A-operand) + V fragments (A-operand), direct global ----
        short8v kf[2][2], vf[4];
#pragma unroll
        for (int kt = 0; kt < 2; ++kt) {
            const unsigned short* krow = kbase + (size_t)(k0 + kt * 16 + mlane) * QKVD;
            kf[kt][0] = *(const short8v*)(krow + quad * 8);
            kf[kt][1] = *(const short8v*)(krow + 32 + quad * 8);
        }
#pragma unroll
        for (int mt = 0; mt < 4; ++mt)
            vf[mt] = *(const short8v*)(vbase + (size_t)(mt * 16 + mlane) * SEQ + k0 + quad * 8);

        // ---- S^T = K·Q^T ----
        floatx4 st[2];
#pragma unroll
        for (int kt = 0; kt < 2; ++kt) {
            floatx4 z = {0, 0, 0, 0};
            st[kt] = __builtin_amdgcn_mfma_f32_16x16x32_bf16(kf[kt][0], qf0, z, 0, 0, 0);
            st[kt] = __builtin_amdgcn_mfma_f32_16x16x32_bf16(kf[kt][1], qf1, st[kt], 0, 0, 0);
        }

        // ---- scale + causal mask (last window only) ----
        float s[2][4];
#pragma unroll
        for (int kt = 0; kt < 2; ++kt)
#pragma unroll
            for (int rg = 0; rg < 4; ++rg) s[kt][rg] = st[kt][rg] * 0.125f;
        if (k0 == klast) {
#pragma unroll
            for (int kt = 0; kt < 2; ++kt)
#pragma unroll
                for (int rg = 0; rg < 4; ++rg)
                    if (k0 + kt * 16 + quad * 4 + rg > myq) s[kt][rg] = -1e30f;
        }

        // ---- online softmax (per-query = per-lane scalar state) ----
        float tm = s[0][0];
#pragma unroll
        for (int kt = 0; kt < 2; ++kt)
#pragma unroll
            for (int rg = 0; rg < 4; ++rg) tm = fmaxf(tm, s[kt][rg]);
        tm = fmaxf(tm, __shfl_xor(tm, 16));
        tm = fmaxf(tm, __shfl_xor(tm, 32));
        const float newm = fmaxf(m_r, tm);
        const float alpha = __expf(m_r - newm);
        m_r = newm;
        float pA[4], pB[4];
        float psum = 0.0f;
#pragma unroll
        for (int rg = 0; rg < 4; ++rg) {
            pA[rg] = __expf(s[0][rg] - newm);
            pB[rg] = __expf(s[1][rg] - newm);
            psum += pA[rg] + pB[rg];
        }
        psum += __shfl_xor(psum, 16);
        psum += __shfl_xor(psum, 32);
        l_r = l_r * alpha + psum;
#pragma unroll
        for (int mt = 0; mt < 4; ++mt)
#pragma unroll
            for (int rg = 0; rg < 4; ++rg) ot[mt][rg] *= alpha;

        // ---- build P^T B-fragment: lane needs keys quad*8+j (j=0..7), query=mlane ----
        short8v pf;
#pragma unroll
        for (int j = 0; j < 8; ++j) {
            const int src = (((quad & 1) * 2 + (j >> 2)) << 4) + mlane;
            const float v0 = __shfl(pA[j & 3], src);
            const float v1 = __shfl(pB[j & 3], src);
            pf[j] = (short)f2bf(quad >= 2 ? v1 : v0);
        }

        // ---- O^T += V^T · P^T ----
#pragma unroll
        for (int mt = 0; mt < 4; ++mt)
            ot[mt] = __builtin_amdgcn_mfma_f32_16x16x32_bf16(vf[mt], pf, ot[mt], 0, 0, 0);
    }

    // ---- epilogue: O^T C-layout row=dim(quad*4+rg + mt*16), col=query(mlane) ----
    const float inv = 1.0f / l_r;
    unsigned short* orow = o + (bS + wq0 + mlane) * BDIM + h * DHEAD;
#pragma unroll
    for (int mt = 0; mt < 4; ++mt) {
        uint2 pk;
        pk.x = (unsigned int)f2bf(ot[mt][0] * inv) | ((unsigned int)f2bf(ot[mt][1] * inv) << 16);
        pk.y = (unsigned int)f2bf(ot[mt][2] * inv) | ((unsigned int)f2bf(ot[mt][3] * inv) << 16);
        *(uint2*)(orow + mt * 16 + quad * 4) = pk;
    }
}

extern "C" void kernel_launch(void* const* d_in, const int* in_sizes, int n_in,
                              void* d_out, int out_size, void* d_ws, size_t ws_size,
                              hipStream_t stream) {
    const int M = 2 * SEQ;  // 4096

    const float* x = (const float*)d_in[0];
    const float* ln1_g = (const float*)d_in[1];
    const float* ln1_b = (const float*)d_in[2];
    const float* wq = (const float*)d_in[3];
    const float* bq = (const float*)d_in[4];
    const float* wk = (const float*)d_in[5];
    const float* bk = (const float*)d_in[6];
    const float* wv = (const float*)d_in[7];
    const float* bv = (const float*)d_in[8];
    const float* wo = (const float*)d_in[9];
    const float* bo = (const float*)d_in[10];
    const float* ln2_g = (const float*)d_in[11];
    const float* ln2_b = (const float*)d_in[12];
    const float* w1 = (const float*)d_in[13];
    const float* b1 = (const float*)d_in[14];
    const float* w2 = (const float*)d_in[15];
    const float* b2 = (const float*)d_in[16];

    char* wsb = (char*)d_ws;
    unsigned short* qkv = (unsigned short*)wsb;                    // [M][3072]
    unsigned short* ffn = (unsigned short*)wsb;                    // [M][4096] (later)
    unsigned short* vt = (unsigned short*)(wsb + (24u << 20));     // [32][64][2048]
    unsigned short* hbuf = (unsigned short*)(wsb + (32u << 20));   // h then o
    float* add1 = (float*)(wsb + (40u << 20));
    unsigned short* h2 = (unsigned short*)(wsb + (56u << 20));
    unsigned short* qkvT = (unsigned short*)(wsb + (64u << 20));
    unsigned short* woT = (unsigned short*)(wsb + (70u << 20));
    unsigned short* w1T = (unsigned short*)(wsb + (72u << 20));
    unsigned short* w2T = (unsigned short*)(wsb + (80u << 20));
    float* bqkv = (float*)(wsb + (88u << 20));

    // 0. weight convert+transpose, bias concat
    transpose_bf16<<<dim3(32, 32), 256, 0, stream>>>(wq, qkvT, 1024, 1024);
    transpose_bf16<<<dim3(32, 32), 256, 0, stream>>>(wk, qkvT + 1024 * 1024, 1024, 1024);
    transpose_bf16<<<dim3(32, 32), 256, 0, stream>>>(wv, qkvT + 2048 * 1024, 1024, 1024);
    transpose_bf16<<<dim3(32, 32), 256, 0, stream>>>(wo, woT, 1024, 1024);
    transpose_bf16<<<dim3(128, 32), 256, 0, stream>>>(w1, w1T, 1024, 4096);
    transpose_bf16<<<dim3(32, 128), 256, 0, stream>>>(w2, w2T, 4096, 1024);
    concat_bias<<<12, 256, 0, stream>>>(bq, bk, bv, bqkv);

    // 1. h = LN1(x) -> bf16
    ln_kernel<<<M, 256, 0, stream>>>(x, ln1_g, ln1_b, hbuf);

    // 2. qkv = h @ [wq|wk|wv] + bias
    mfma_gemm<128, 0, 0, 1><<<dim3(QKVD / 128, M / 128), 256, 0, stream>>>(
        hbuf, qkvT, bqkv, nullptr, qkv, M, QKVD, 1024);

    // 2b. vt = V^T per (b,h)
    transpose_v<<<dim3(SEQ / 64, 32), 256, 0, stream>>>(qkv, vt);

    // 3. o = causal_attention(qkv) -> hbuf
    attn_kernel<<<dim3(SEQ / 64, NH, 2), 256, 0, stream>>>(qkv, vt, hbuf);

    // 4. add1 = o @ wo + bo + x (fp32)
    mfma_gemm<64, 1, 0, 0><<<dim3(1024 / 64, M / 128), 256, 0, stream>>>(
        hbuf, woT, bo, x, add1, M, 1024, 1024);

    // 5. h2 = LN2(add1) -> bf16
    ln_kernel<<<M, 256, 0, stream>>>(add1, ln2_g, ln2_b, h2);

    // 6. ffn = gelu(h2 @ w1 + b1) -> bf16 (overwrites qkv+vt region; both dead)
    mfma_gemm<128, 0, 1, 1><<<dim3(FDIM / 128, M / 128), 256, 0, stream>>>(
        h2, w1T, b1, nullptr, ffn, M, FDIM, 1024);

    // 7. out = ffn @ w2 + b2 + add1 -> fp32 d_out
    mfma_gemm<64, 1, 0, 0><<<dim3(1024 / 64, M / 128), 256, 0, stream>>>(
        ffn, w2T, b2, add1, (float*)d_out, M, 1024, FDIM);
}

// Round 5
// 473.336 us; speedup vs baseline: 4.9449x; 1.2328x over previous
//
#include <hip/hip_runtime.h>
#include <hip/hip_bf16.h>

// GPT2 block fwd: B=2,S=2048,D=1024,H=16,DH=64,F=4096. fp32 in/out, bf16 MFMA.
// ws layout (bytes):
//   [0,24M)   qkv bf16 [4096][3072]   (slot reused by ffn [4096][4096] bf16 = 32MB)
//   [24M,32M) vt bf16 [32 bh][64 d][2048 s]  (live only between QKV gemm and attn)
//   [32M,40M) hbuf bf16: h (LN1 out), later attention output o
//   [40M,56M) add1 fp32 [4096][1024]
//   [56M,64M) h2 bf16
//   [64M,70M) qkvT bf16 | [70M,72M) woT | [72M,80M) w1T | [80M,88M) w2T
//   [88M,..)  bias_qkv fp32 [3072]
// total ~88MB.

#define BDIM 1024
#define SEQ 2048
#define NH 16
#define DHEAD 64
#define FDIM 4096
#define QKVD 3072

typedef __attribute__((ext_vector_type(8))) short short8v;
typedef __attribute__((ext_vector_type(4))) float floatx4;

__device__ __forceinline__ unsigned short f2bf(float f) {
    unsigned int u = __float_as_uint(f);
    unsigned int r = u + 0x7FFFu + ((u >> 16) & 1u);
    return (unsigned short)(r >> 16);
}
__device__ __forceinline__ unsigned int pack2bf(float a, float b) {
    return (unsigned int)f2bf(a) | ((unsigned int)f2bf(b) << 16);
}

__device__ __forceinline__ void load16_lds(const unsigned short* g, short* l) {
    __builtin_amdgcn_global_load_lds((const __attribute__((address_space(1))) void*)g,
                                     (__attribute__((address_space(3))) void*)l, 16, 0, 0);
}

// ---------------- weight fp32 [K,N] -> bf16 [N,K] transpose ----------------
__global__ __launch_bounds__(256) void transpose_bf16(const float* __restrict__ W,
                                                      unsigned short* __restrict__ Wt,
                                                      int K, int N) {
    __shared__ float tile[32][33];
    const int t = threadIdx.x;
    const int r = t >> 3, c4 = (t & 7) * 4;
    const int n0 = blockIdx.x * 32, k0 = blockIdx.y * 32;
    float4 p = *(const float4*)(W + (size_t)(k0 + r) * N + n0 + c4);
    tile[r][c4 + 0] = p.x;
    tile[r][c4 + 1] = p.y;
    tile[r][c4 + 2] = p.z;
    tile[r][c4 + 3] = p.w;
    __syncthreads();
    ushort4 ou;
    ou.x = f2bf(tile[c4 + 0][r]);
    ou.y = f2bf(tile[c4 + 1][r]);
    ou.z = f2bf(tile[c4 + 2][r]);
    ou.w = f2bf(tile[c4 + 3][r]);
    *(ushort4*)(Wt + (size_t)(n0 + r) * K + k0 + c4) = ou;
}

__global__ void concat_bias(const float* __restrict__ a, const float* __restrict__ b,
                            const float* __restrict__ c, float* __restrict__ out) {
    int i = blockIdx.x * 256 + threadIdx.x;
    out[i] = (i < 1024) ? a[i] : (i < 2048 ? b[i - 1024] : c[i - 2048]);
}

// ---------------- V transpose: qkv V-cols -> vt[bh][d][s] ----------------
__global__ __launch_bounds__(256) void transpose_v(const unsigned short* __restrict__ qkv,
                                                   unsigned short* __restrict__ vt) {
    const int bh = blockIdx.y;
    const int b = bh >> 4, h = bh & 15;
    const int s0 = blockIdx.x * 64;
    __shared__ unsigned short tile[64][80];
    const int t = threadIdx.x;
#pragma unroll
    for (int j = 0; j < 2; ++j) {
        const int c = j * 256 + t;
        const int s = c >> 3, d8 = (c & 7) * 8;
        uint4 p = *(const uint4*)(qkv + (size_t)(b * SEQ + s0 + s) * QKVD + 2048 + h * 64 + d8);
        *(uint4*)&tile[s][d8] = p;
    }
    __syncthreads();
#pragma unroll
    for (int j = 0; j < 2; ++j) {
        const int c = j * 256 + t;
        const int d = c >> 3, s8 = (c & 7) * 8;
        unsigned int w0 = (unsigned int)tile[s8 + 0][d] | ((unsigned int)tile[s8 + 1][d] << 16);
        unsigned int w1 = (unsigned int)tile[s8 + 2][d] | ((unsigned int)tile[s8 + 3][d] << 16);
        unsigned int w2 = (unsigned int)tile[s8 + 4][d] | ((unsigned int)tile[s8 + 5][d] << 16);
        unsigned int w3 = (unsigned int)tile[s8 + 6][d] | ((unsigned int)tile[s8 + 7][d] << 16);
        uint4 o = {w0, w1, w2, w3};
        *(uint4*)(vt + ((size_t)bh * 64 + d) * SEQ + s0 + s8) = o;
    }
}

// ---------------- LayerNorm: fp32 in -> bf16 out ----------------
__global__ __launch_bounds__(256) void ln_kernel(const float* __restrict__ x,
                                                 const float* __restrict__ g,
                                                 const float* __restrict__ bb,
                                                 unsigned short* __restrict__ out) {
    const int row = blockIdx.x;
    const int t = threadIdx.x;
    const int c = t * 4;
    float4 p = *(const float4*)(x + (size_t)row * BDIM + c);
    float s = p.x + p.y + p.z + p.w;
    float sq = p.x * p.x + p.y * p.y + p.z * p.z + p.w * p.w;
    for (int off = 1; off < 64; off <<= 1) {
        s += __shfl_xor(s, off);
        sq += __shfl_xor(sq, off);
    }
    __shared__ float ssum[4], ssq[4];
    const int wave = t >> 6, lane = t & 63;
    if (lane == 0) { ssum[wave] = s; ssq[wave] = sq; }
    __syncthreads();
    s = ssum[0] + ssum[1] + ssum[2] + ssum[3];
    sq = ssq[0] + ssq[1] + ssq[2] + ssq[3];
    const float mean = s * (1.0f / BDIM);
    const float var = sq * (1.0f / BDIM) - mean * mean;
    const float rstd = rsqrtf(var + 1e-5f);
    float4 gg = *(const float4*)(g + c);
    float4 bv = *(const float4*)(bb + c);
    ushort4 o;
    o.x = f2bf((p.x - mean) * rstd * gg.x + bv.x);
    o.y = f2bf((p.y - mean) * rstd * gg.y + bv.y);
    o.z = f2bf((p.z - mean) * rstd * gg.z + bv.z);
    o.w = f2bf((p.w - mean) * rstd * gg.w + bv.w);
    *(ushort4*)(out + (size_t)row * BDIM + c) = o;
}

// ---------------- MFMA GEMM ----------------
// QSCALE: multiply output cols < 1024 by 0.125 (pre-scales Q for attention).
template <int BN, int RES, int GELU, int OBF16, int QSCALE = 0>
__global__ __launch_bounds__(256) void mfma_gemm(const unsigned short* __restrict__ A,
                                                 const unsigned short* __restrict__ Bt,
                                                 const float* __restrict__ bias,
                                                 const float* __restrict__ res,
                                                 void* __restrict__ Cv,
                                                 int M, int N, int K) {
    constexpr int MI = (BN == 128) ? 4 : 2;
    __shared__ short As[128 * 32];
    __shared__ short Bs[BN * 32];
    const int t = threadIdx.x;
    const int wave = t >> 6, lane = t & 63;
    const int m0 = blockIdx.y * 128, n0 = blockIdx.x * BN;
    const int wmrow = (BN == 128) ? (wave & 1) * 64 : wave * 32;
    const int wnrow = (BN == 128) ? (wave >> 1) * 64 : 0;
    const int mlane = lane & 15, quad = lane >> 4;

    floatx4 acc[MI][4];
#pragma unroll
    for (int mi = 0; mi < MI; ++mi)
#pragma unroll
        for (int ni = 0; ni < 4; ++ni) {
            floatx4 z = {0.0f, 0.0f, 0.0f, 0.0f};
            acc[mi][ni] = z;
        }

    for (int k0 = 0; k0 < K; k0 += 32) {
        __syncthreads();
#pragma unroll
        for (int j = 0; j < 2; ++j) {
            const int c = j * 256 + wave * 64 + lane;
            load16_lds(A + (size_t)(m0 + (c >> 2)) * K + k0 + (c & 3) * 8, &As[c * 8]);
        }
#pragma unroll
        for (int j = 0; j < BN / 64; ++j) {
            const int c = j * 256 + wave * 64 + lane;
            load16_lds(Bt + (size_t)(n0 + (c >> 2)) * K + k0 + (c & 3) * 8, &Bs[c * 8]);
        }
        __syncthreads();
        short8v a[MI], b[4];
#pragma unroll
        for (int mi = 0; mi < MI; ++mi)
            a[mi] = *(const short8v*)&As[(wmrow + mi * 16 + mlane) * 32 + quad * 8];
#pragma unroll
        for (int ni = 0; ni < 4; ++ni)
            b[ni] = *(const short8v*)&Bs[(wnrow + ni * 16 + mlane) * 32 + quad * 8];
#pragma unroll
        for (int mi = 0; mi < MI; ++mi)
#pragma unroll
            for (int ni = 0; ni < 4; ++ni)
                acc[mi][ni] = __builtin_amdgcn_mfma_f32_16x16x32_bf16(a[mi], b[ni], acc[mi][ni], 0, 0, 0);
    }
#pragma unroll
    for (int mi = 0; mi < MI; ++mi) {
#pragma unroll
        for (int ni = 0; ni < 4; ++ni) {
            const int col = n0 + wnrow + ni * 16 + mlane;
            const float bv = bias[col];
#pragma unroll
            for (int rg = 0; rg < 4; ++rg) {
                const int row = m0 + wmrow + mi * 16 + quad * 4 + rg;
                float v = acc[mi][ni][rg] + bv;
                if (RES) v += res[(size_t)row * N + col];
                if (GELU) v = 0.5f * v * (1.0f + erff(v * 0.70710678118654752f));
                if (QSCALE && col < 1024) v *= 0.125f;
                if (OBF16)
                    ((unsigned short*)Cv)[(size_t)row * N + col] = f2bf(v);
                else
                    ((float*)Cv)[(size_t)row * N + col] = v;
            }
        }
    }
}

// ---------------- MFMA flash attention (causal), barrier-free ----------------
// 4 waves/block, 32 queries/wave (two n=16 groups), 32-key windows, K/V register
// prefetch, P^T transpose via per-wave LDS round-trip (no __syncthreads anywhere).
// Q pre-scaled by 0.125 in the QKV GEMM epilogue.
__device__ __forceinline__ void load_kv(const unsigned short* kbase, const unsigned short* vbase,
                                        int k0, int mlane, int quad,
                                        short8v kf[2][2], short8v vf[4]) {
#pragma unroll
    for (int kt = 0; kt < 2; ++kt) {
        const unsigned short* krow = kbase + (size_t)(k0 + kt * 16 + mlane) * QKVD;
        kf[kt][0] = *(const short8v*)(krow + quad * 8);
        kf[kt][1] = *(const short8v*)(krow + 32 + quad * 8);
    }
#pragma unroll
    for (int mt = 0; mt < 4; ++mt)
        vf[mt] = *(const short8v*)(vbase + (size_t)(mt * 16 + mlane) * SEQ + k0 + quad * 8);
}

__global__ __launch_bounds__(256) void attn_kernel(const unsigned short* __restrict__ qkv,
                                                   const unsigned short* __restrict__ vt,
                                                   unsigned short* __restrict__ o) {
    const int b = blockIdx.z, h = blockIdx.y;
    const int qt = gridDim.x - 1 - blockIdx.x;  // big blocks first
    const int wave = threadIdx.x >> 6, lane = threadIdx.x & 63;
    const int mlane = lane & 15, quad = lane >> 4;
    const int wq0 = qt * 128 + wave * 32;
    const size_t bS = (size_t)b * SEQ;

    // per-wave P^T staging: [ng][query][key], key-padded to 40 (80B row: 2-way banks)
    __shared__ __align__(16) unsigned short plds_all[4][2][16][40];

    // Q fragments (B-operand), held all kernel. qf[ng][i]: queries wq0+ng*16+mlane.
    short8v qf[2][2];
#pragma unroll
    for (int ng = 0; ng < 2; ++ng) {
        const unsigned short* qrow = qkv + (bS + wq0 + ng * 16 + mlane) * QKVD + h * DHEAD;
        qf[ng][0] = *(const short8v*)(qrow + quad * 8);
        qf[ng][1] = *(const short8v*)(qrow + 32 + quad * 8);
    }

    const unsigned short* kbase = qkv + bS * QKVD + 1024 + h * DHEAD;
    const unsigned short* vbase = vt + ((size_t)(b * NH + h)) * DHEAD * SEQ;

    floatx4 ot[2][4];
#pragma unroll
    for (int ng = 0; ng < 2; ++ng)
#pragma unroll
        for (int mt = 0; mt < 4; ++mt) { floatx4 z = {0, 0, 0, 0}; ot[ng][mt] = z; }
    float m_r[2] = {-INFINITY, -INFINITY}, l_r[2] = {0.0f, 0.0f};

    const int kend = wq0 + 32;
    short8v kf[2][2], vf[4];
    load_kv(kbase, vbase, 0, mlane, quad, kf, vf);

    for (int k0 = 0; k0 < kend; k0 += 32) {
        // ---- prefetch next window ----
        short8v kn[2][2], vn[4];
        if (k0 + 32 < kend) load_kv(kbase, vbase, k0 + 32, mlane, quad, kn, vn);

        // ---- S^T = K·Q^T (Q pre-scaled) ----
        floatx4 st[2][2];
#pragma unroll
        for (int ng = 0; ng < 2; ++ng)
#pragma unroll
            for (int kt = 0; kt < 2; ++kt) {
                floatx4 z = {0, 0, 0, 0};
                st[ng][kt] = __builtin_amdgcn_mfma_f32_16x16x32_bf16(kf[kt][0], qf[ng][0], z, 0, 0, 0);
                st[ng][kt] = __builtin_amdgcn_mfma_f32_16x16x32_bf16(kf[kt][1], qf[ng][1], st[ng][kt], 0, 0, 0);
            }

        // ---- causal mask (only the last window straddles the diagonal) ----
        if (k0 == wq0) {
#pragma unroll
            for (int ng = 0; ng < 2; ++ng)
#pragma unroll
                for (int kt = 0; kt < 2; ++kt)
#pragma unroll
                    for (int rg = 0; rg < 4; ++rg)
                        if (k0 + kt * 16 + quad * 4 + rg > wq0 + ng * 16 + mlane)
                            st[ng][kt][rg] = -1e30f;
        }

        // ---- online softmax (state = scalar per lane per ng) + P^T to LDS ----
#pragma unroll
        for (int ng = 0; ng < 2; ++ng) {
            float tm = st[ng][0][0];
#pragma unroll
            for (int kt = 0; kt < 2; ++kt)
#pragma unroll
                for (int rg = 0; rg < 4; ++rg) tm = fmaxf(tm, st[ng][kt][rg]);
            tm = fmaxf(tm, __shfl_xor(tm, 16));
            tm = fmaxf(tm, __shfl_xor(tm, 32));
            const float newm = fmaxf(m_r[ng], tm);
            const float alpha = __expf(m_r[ng] - newm);
            m_r[ng] = newm;
            float p[2][4], psum = 0.0f;
#pragma unroll
            for (int kt = 0; kt < 2; ++kt)
#pragma unroll
                for (int rg = 0; rg < 4; ++rg) {
                    p[kt][rg] = __expf(st[ng][kt][rg] - newm);
                    psum += p[kt][rg];
                }
            psum += __shfl_xor(psum, 16);
            psum += __shfl_xor(psum, 32);
            l_r[ng] = l_r[ng] * alpha + psum;
#pragma unroll
            for (int mt = 0; mt < 4; ++mt)
#pragma unroll
                for (int rg = 0; rg < 4; ++rg) ot[ng][mt][rg] *= alpha;
#pragma unroll
            for (int kt = 0; kt < 2; ++kt) {
                uint2 pk;
                pk.x = pack2bf(p[kt][0], p[kt][1]);
                pk.y = pack2bf(p[kt][2], p[kt][3]);
                *(uint2*)&plds_all[wave][ng][mlane][kt * 16 + quad * 4] = pk;
            }
        }

        // ---- O^T += V^T · P^T  (LDS read: in-order per-wave, no barrier) ----
#pragma unroll
        for (int ng = 0; ng < 2; ++ng) {
            short8v pf = *(const short8v*)&plds_all[wave][ng][mlane][quad * 8];
#pragma unroll
            for (int mt = 0; mt < 4; ++mt)
                ot[ng][mt] = __builtin_amdgcn_mfma_f32_16x16x32_bf16(vf[mt], pf, ot[ng][mt], 0, 0, 0);
        }

        // ---- rotate prefetch ----
#pragma unroll
        for (int kt = 0; kt < 2; ++kt) { kf[kt][0] = kn[kt][0]; kf[kt][1] = kn[kt][1]; }
#pragma unroll
        for (int mt = 0; mt < 4; ++mt) vf[mt] = vn[mt];
    }

    // ---- epilogue ----
#pragma unroll
    for (int ng = 0; ng < 2; ++ng) {
        const float inv = 1.0f / l_r[ng];
        unsigned short* orow = o + (bS + wq0 + ng * 16 + mlane) * BDIM + h * DHEAD;
#pragma unroll
        for (int mt = 0; mt < 4; ++mt) {
            uint2 pk;
            pk.x = pack2bf(ot[ng][mt][0] * inv, ot[ng][mt][1] * inv);
            pk.y = pack2bf(ot[ng][mt][2] * inv, ot[ng][mt][3] * inv);
            *(uint2*)(orow + mt * 16 + quad * 4) = pk;
        }
    }
}

extern "C" void kernel_launch(void* const* d_in, const int* in_sizes, int n_in,
                              void* d_out, int out_size, void* d_ws, size_t ws_size,
                              hipStream_t stream) {
    const int M = 2 * SEQ;  // 4096

    const float* x = (const float*)d_in[0];
    const float* ln1_g = (const float*)d_in[1];
    const float* ln1_b = (const float*)d_in[2];
    const float* wq = (const float*)d_in[3];
    const float* bq = (const float*)d_in[4];
    const float* wk = (const float*)d_in[5];
    const float* bk = (const float*)d_in[6];
    const float* wv = (const float*)d_in[7];
    const float* bv = (const float*)d_in[8];
    const float* wo = (const float*)d_in[9];
    const float* bo = (const float*)d_in[10];
    const float* ln2_g = (const float*)d_in[11];
    const float* ln2_b = (const float*)d_in[12];
    const float* w1 = (const float*)d_in[13];
    const float* b1 = (const float*)d_in[14];
    const float* w2 = (const float*)d_in[15];
    const float* b2 = (const float*)d_in[16];

    char* wsb = (char*)d_ws;
    unsigned short* qkv = (unsigned short*)wsb;                    // [M][3072]
    unsigned short* ffn = (unsigned short*)wsb;                    // [M][4096] (later)
    unsigned short* vt = (unsigned short*)(wsb + (24u << 20));     // [32][64][2048]
    unsigned short* hbuf = (unsigned short*)(wsb + (32u << 20));   // h then o
    float* add1 = (float*)(wsb + (40u << 20));
    unsigned short* h2 = (unsigned short*)(wsb + (56u << 20));
    unsigned short* qkvT = (unsigned short*)(wsb + (64u << 20));
    unsigned short* woT = (unsigned short*)(wsb + (70u << 20));
    unsigned short* w1T = (unsigned short*)(wsb + (72u << 20));
    unsigned short* w2T = (unsigned short*)(wsb + (80u << 20));
    float* bqkv = (float*)(wsb + (88u << 20));

    // 0. weight convert+transpose, bias concat
    transpose_bf16<<<dim3(32, 32), 256, 0, stream>>>(wq, qkvT, 1024, 1024);
    transpose_bf16<<<dim3(32, 32), 256, 0, stream>>>(wk, qkvT + 1024 * 1024, 1024, 1024);
    transpose_bf16<<<dim3(32, 32), 256, 0, stream>>>(wv, qkvT + 2048 * 1024, 1024, 1024);
    transpose_bf16<<<dim3(32, 32), 256, 0, stream>>>(wo, woT, 1024, 1024);
    transpose_bf16<<<dim3(128, 32), 256, 0, stream>>>(w1, w1T, 1024, 4096);
    transpose_bf16<<<dim3(32, 128), 256, 0, stream>>>(w2, w2T, 4096, 1024);
    concat_bias<<<12, 256, 0, stream>>>(bq, bk, bv, bqkv);

    // 1. h = LN1(x) -> bf16
    ln_kernel<<<M, 256, 0, stream>>>(x, ln1_g, ln1_b, hbuf);

    // 2. qkv = h @ [wq|wk|wv] + bias; Q columns pre-scaled by 0.125
    mfma_gemm<128, 0, 0, 1, 1><<<dim3(QKVD / 128, M / 128), 256, 0, stream>>>(
        hbuf, qkvT, bqkv, nullptr, qkv, M, QKVD, 1024);

    // 2b. vt = V^T per (b,h)
    transpose_v<<<dim3(SEQ / 64, 32), 256, 0, stream>>>(qkv, vt);

    // 3. o = causal_attention(qkv) -> hbuf
    attn_kernel<<<dim3(SEQ / 128, NH, 2), 256, 0, stream>>>(qkv, vt, hbuf);

    // 4. add1 = o @ wo + bo + x (fp32)
    mfma_gemm<64, 1, 0, 0><<<dim3(1024 / 64, M / 128), 256, 0, stream>>>(
        hbuf, woT, bo, x, add1, M, 1024, 1024);

    // 5. h2 = LN2(add1) -> bf16
    ln_kernel<<<M, 256, 0, stream>>>(add1, ln2_g, ln2_b, h2);

    // 6. ffn = gelu(h2 @ w1 + b1) -> bf16 (overwrites qkv+vt region; both dead)
    mfma_gemm<128, 0, 1, 1><<<dim3(FDIM / 128, M / 128), 256, 0, stream>>>(
        h2, w1T, b1, nullptr, ffn, M, FDIM, 1024);

    // 7. out = ffn @ w2 + b2 + add1 -> fp32 d_out
    mfma_gemm<64, 1, 0, 0><<<dim3(1024 / 64, M / 128), 256, 0, stream>>>(
        ffn, w2T, b2, add1, (float*)d_out, M, 1024, FDIM);
}

// Round 6
// 426.139 us; speedup vs baseline: 5.4926x; 1.1108x over previous
//
#include <hip/hip_runtime.h>
#include <hip/hip_bf16.h>

// GPT2 block fwd: B=2,S=2048,D=1024,H=16,DH=64,F=4096. fp32 in/out, bf16 MFMA.
// ws layout (bytes):
//   [0,24M)   qkv bf16 [4096][3072]   (slot reused by ffn [4096][4096] bf16 = 32MB)
//   [24M,32M) vt bf16 [32 bh][64 d][2048 s]  (live only between QKV gemm and attn)
//   [32M,40M) hbuf bf16: h (LN1 out), later attention output o
//   [40M,56M) add1 fp32 [4096][1024]
//   [56M,64M) h2 bf16
//   [64M,70M) qkvT bf16 | [70M,72M) woT | [72M,80M) w1T | [80M,88M) w2T
//   [88M,..)  bias_qkv fp32 [3072]
// total ~88MB.

#define BDIM 1024
#define SEQ 2048
#define NH 16
#define DHEAD 64
#define FDIM 4096
#define QKVD 3072

typedef __attribute__((ext_vector_type(8))) short short8v;
typedef __attribute__((ext_vector_type(4))) float floatx4;

__device__ __forceinline__ unsigned short f2bf(float f) {
    unsigned int u = __float_as_uint(f);
    unsigned int r = u + 0x7FFFu + ((u >> 16) & 1u);
    return (unsigned short)(r >> 16);
}
__device__ __forceinline__ unsigned int pack2bf(float a, float b) {
    return (unsigned int)f2bf(a) | ((unsigned int)f2bf(b) << 16);
}

__device__ __forceinline__ void load16_lds(const unsigned short* g, short* l) {
    __builtin_amdgcn_global_load_lds((const __attribute__((address_space(1))) void*)g,
                                     (__attribute__((address_space(3))) void*)l, 16, 0, 0);
}

// ---------------- weight fp32 [K,N] -> bf16 [N,K] transpose ----------------
__global__ __launch_bounds__(256) void transpose_bf16(const float* __restrict__ W,
                                                      unsigned short* __restrict__ Wt,
                                                      int K, int N) {
    __shared__ float tile[32][33];
    const int t = threadIdx.x;
    const int r = t >> 3, c4 = (t & 7) * 4;
    const int n0 = blockIdx.x * 32, k0 = blockIdx.y * 32;
    float4 p = *(const float4*)(W + (size_t)(k0 + r) * N + n0 + c4);
    tile[r][c4 + 0] = p.x;
    tile[r][c4 + 1] = p.y;
    tile[r][c4 + 2] = p.z;
    tile[r][c4 + 3] = p.w;
    __syncthreads();
    ushort4 ou;
    ou.x = f2bf(tile[c4 + 0][r]);
    ou.y = f2bf(tile[c4 + 1][r]);
    ou.z = f2bf(tile[c4 + 2][r]);
    ou.w = f2bf(tile[c4 + 3][r]);
    *(ushort4*)(Wt + (size_t)(n0 + r) * K + k0 + c4) = ou;
}

__global__ void concat_bias(const float* __restrict__ a, const float* __restrict__ b,
                            const float* __restrict__ c, float* __restrict__ out) {
    int i = blockIdx.x * 256 + threadIdx.x;
    out[i] = (i < 1024) ? a[i] : (i < 2048 ? b[i - 1024] : c[i - 2048]);
}

// ---------------- V transpose: qkv V-cols -> vt[bh][d][s] ----------------
__global__ __launch_bounds__(256) void transpose_v(const unsigned short* __restrict__ qkv,
                                                   unsigned short* __restrict__ vt) {
    const int bh = blockIdx.y;
    const int b = bh >> 4, h = bh & 15;
    const int s0 = blockIdx.x * 64;
    __shared__ unsigned short tile[64][80];
    const int t = threadIdx.x;
#pragma unroll
    for (int j = 0; j < 2; ++j) {
        const int c = j * 256 + t;
        const int s = c >> 3, d8 = (c & 7) * 8;
        uint4 p = *(const uint4*)(qkv + (size_t)(b * SEQ + s0 + s) * QKVD + 2048 + h * 64 + d8);
        *(uint4*)&tile[s][d8] = p;
    }
    __syncthreads();
#pragma unroll
    for (int j = 0; j < 2; ++j) {
        const int c = j * 256 + t;
        const int d = c >> 3, s8 = (c & 7) * 8;
        unsigned int w0 = (unsigned int)tile[s8 + 0][d] | ((unsigned int)tile[s8 + 1][d] << 16);
        unsigned int w1 = (unsigned int)tile[s8 + 2][d] | ((unsigned int)tile[s8 + 3][d] << 16);
        unsigned int w2 = (unsigned int)tile[s8 + 4][d] | ((unsigned int)tile[s8 + 5][d] << 16);
        unsigned int w3 = (unsigned int)tile[s8 + 6][d] | ((unsigned int)tile[s8 + 7][d] << 16);
        uint4 o = {w0, w1, w2, w3};
        *(uint4*)(vt + ((size_t)bh * 64 + d) * SEQ + s0 + s8) = o;
    }
}

// ---------------- LayerNorm: fp32 in -> bf16 out ----------------
__global__ __launch_bounds__(256) void ln_kernel(const float* __restrict__ x,
                                                 const float* __restrict__ g,
                                                 const float* __restrict__ bb,
                                                 unsigned short* __restrict__ out) {
    const int row = blockIdx.x;
    const int t = threadIdx.x;
    const int c = t * 4;
    float4 p = *(const float4*)(x + (size_t)row * BDIM + c);
    float s = p.x + p.y + p.z + p.w;
    float sq = p.x * p.x + p.y * p.y + p.z * p.z + p.w * p.w;
    for (int off = 1; off < 64; off <<= 1) {
        s += __shfl_xor(s, off);
        sq += __shfl_xor(sq, off);
    }
    __shared__ float ssum[4], ssq[4];
    const int wave = t >> 6, lane = t & 63;
    if (lane == 0) { ssum[wave] = s; ssq[wave] = sq; }
    __syncthreads();
    s = ssum[0] + ssum[1] + ssum[2] + ssum[3];
    sq = ssq[0] + ssq[1] + ssq[2] + ssq[3];
    const float mean = s * (1.0f / BDIM);
    const float var = sq * (1.0f / BDIM) - mean * mean;
    const float rstd = rsqrtf(var + 1e-5f);
    float4 gg = *(const float4*)(g + c);
    float4 bv = *(const float4*)(bb + c);
    ushort4 o;
    o.x = f2bf((p.x - mean) * rstd * gg.x + bv.x);
    o.y = f2bf((p.y - mean) * rstd * gg.y + bv.y);
    o.z = f2bf((p.z - mean) * rstd * gg.z + bv.z);
    o.w = f2bf((p.w - mean) * rstd * gg.w + bv.w);
    *(ushort4*)(out + (size_t)row * BDIM + c) = o;
}

// ---------------- MFMA GEMM ----------------
// QSCALE: multiply output cols < 1024 by 0.125 (pre-scales Q for attention).
template <int BN, int RES, int GELU, int OBF16, int QSCALE = 0>
__global__ __launch_bounds__(256) void mfma_gemm(const unsigned short* __restrict__ A,
                                                 const unsigned short* __restrict__ Bt,
                                                 const float* __restrict__ bias,
                                                 const float* __restrict__ res,
                                                 void* __restrict__ Cv,
                                                 int M, int N, int K) {
    constexpr int MI = (BN == 128) ? 4 : 2;
    __shared__ short As[128 * 32];
    __shared__ short Bs[BN * 32];
    const int t = threadIdx.x;
    const int wave = t >> 6, lane = t & 63;
    const int m0 = blockIdx.y * 128, n0 = blockIdx.x * BN;
    const int wmrow = (BN == 128) ? (wave & 1) * 64 : wave * 32;
    const int wnrow = (BN == 128) ? (wave >> 1) * 64 : 0;
    const int mlane = lane & 15, quad = lane >> 4;

    floatx4 acc[MI][4];
#pragma unroll
    for (int mi = 0; mi < MI; ++mi)
#pragma unroll
        for (int ni = 0; ni < 4; ++ni) {
            floatx4 z = {0.0f, 0.0f, 0.0f, 0.0f};
            acc[mi][ni] = z;
        }

    for (int k0 = 0; k0 < K; k0 += 32) {
        __syncthreads();
#pragma unroll
        for (int j = 0; j < 2; ++j) {
            const int c = j * 256 + wave * 64 + lane;
            load16_lds(A + (size_t)(m0 + (c >> 2)) * K + k0 + (c & 3) * 8, &As[c * 8]);
        }
#pragma unroll
        for (int j = 0; j < BN / 64; ++j) {
            const int c = j * 256 + wave * 64 + lane;
            load16_lds(Bt + (size_t)(n0 + (c >> 2)) * K + k0 + (c & 3) * 8, &Bs[c * 8]);
        }
        __syncthreads();
        short8v a[MI], b[4];
#pragma unroll
        for (int mi = 0; mi < MI; ++mi)
            a[mi] = *(const short8v*)&As[(wmrow + mi * 16 + mlane) * 32 + quad * 8];
#pragma unroll
        for (int ni = 0; ni < 4; ++ni)
            b[ni] = *(const short8v*)&Bs[(wnrow + ni * 16 + mlane) * 32 + quad * 8];
#pragma unroll
        for (int mi = 0; mi < MI; ++mi)
#pragma unroll
            for (int ni = 0; ni < 4; ++ni)
                acc[mi][ni] = __builtin_amdgcn_mfma_f32_16x16x32_bf16(a[mi], b[ni], acc[mi][ni], 0, 0, 0);
    }
#pragma unroll
    for (int mi = 0; mi < MI; ++mi) {
#pragma unroll
        for (int ni = 0; ni < 4; ++ni) {
            const int col = n0 + wnrow + ni * 16 + mlane;
            const float bv = bias[col];
#pragma unroll
            for (int rg = 0; rg < 4; ++rg) {
                const int row = m0 + wmrow + mi * 16 + quad * 4 + rg;
                float v = acc[mi][ni][rg] + bv;
                if (RES) v += res[(size_t)row * N + col];
                if (GELU) v = 0.5f * v * (1.0f + erff(v * 0.70710678118654752f));
                if (QSCALE && col < 1024) v *= 0.125f;
                if (OBF16)
                    ((unsigned short*)Cv)[(size_t)row * N + col] = f2bf(v);
                else
                    ((float*)Cv)[(size_t)row * N + col] = v;
            }
        }
    }
}

// ---------------- MFMA flash attention (causal), LDS-staged K/V ----------------
// Block = 4 waves × 32 queries = 128-query tile (tile index qt). Block loop stages
// K (32x64, 144B rows) and V^T (64x32, 80B rows) tiles cooperatively; waves read
// MFMA fragments from LDS (optimal b128 bank patterns). Register prefetch of the
// next tile overlaps compute. qt remapped per-b so co-resident block pairs
// (id, id+256) combine big+small causal tiles (balanced work per CU).
// Q pre-scaled by 0.125 in the QKV GEMM epilogue.
__global__ __launch_bounds__(256) void attn_kernel(const unsigned short* __restrict__ qkv,
                                                   const unsigned short* __restrict__ vt,
                                                   unsigned short* __restrict__ o) {
    const int b = blockIdx.z, h = blockIdx.y;
    const int qt = b ? (int)(gridDim.x - 1 - blockIdx.x) : (int)blockIdx.x;
    const int t = threadIdx.x;
    const int wave = t >> 6, lane = t & 63;
    const int mlane = lane & 15, quad = lane >> 4;
    const int wq0 = qt * 128 + wave * 32;
    const size_t bS = (size_t)b * SEQ;

    __shared__ unsigned short Ks[32][72];                       // 64 data + 8 pad shorts
    __shared__ unsigned short Vs[64][40];                       // 32 data + 8 pad shorts
    __shared__ __align__(16) unsigned short plds[4][2][16][40]; // P^T round-trip

    // Q fragments (B-operand), held all kernel.
    short8v qf[2][2];
#pragma unroll
    for (int ng = 0; ng < 2; ++ng) {
        const unsigned short* qrow = qkv + (bS + wq0 + ng * 16 + mlane) * QKVD + h * DHEAD;
        qf[ng][0] = *(const short8v*)(qrow + quad * 8);
        qf[ng][1] = *(const short8v*)(qrow + 32 + quad * 8);
    }

    const unsigned short* kbase = qkv + bS * QKVD + 1024 + h * DHEAD;
    const unsigned short* vbase = vt + ((size_t)(b * NH + h)) * DHEAD * SEQ;

    // staging addresses for this thread
    const int kr = t >> 3, ko = (t & 7) * 8;   // K: key-row 0..31, dim-offset
    const int vd = t >> 2, vo = (t & 3) * 8;   // V^T: dim-row 0..63, key-offset
    const unsigned short* kg = kbase + (size_t)kr * QKVD + ko;
    const unsigned short* vg = vbase + (size_t)vd * SEQ + vo;

    floatx4 ot[2][4];
#pragma unroll
    for (int ng = 0; ng < 2; ++ng)
#pragma unroll
        for (int mt = 0; mt < 4; ++mt) { floatx4 z = {0, 0, 0, 0}; ot[ng][mt] = z; }
    float m_r[2] = {-INFINITY, -INFINITY}, l_r[2] = {0.0f, 0.0f};

    const int kend = wq0 + 32;          // this wave's causal limit
    const int kmax = qt * 128 + 128;    // block loop limit

    uint4 kreg = *(const uint4*)kg;
    uint4 vreg = *(const uint4*)vg;

    for (int k0 = 0; k0 < kmax; k0 += 32) {
        *(uint4*)&Ks[kr][ko] = kreg;
        *(uint4*)&Vs[vd][vo] = vreg;
        __syncthreads();
        if (k0 + 32 < kmax) {  // prefetch next tile during compute
            kreg = *(const uint4*)(kg + (size_t)(k0 + 32) * QKVD);
            vreg = *(const uint4*)(vg + (k0 + 32));
        }
        if (k0 < kend) {
            short8v kf[2][2], vf[4];
#pragma unroll
            for (int kt = 0; kt < 2; ++kt) {
                kf[kt][0] = *(const short8v*)&Ks[kt * 16 + mlane][quad * 8];
                kf[kt][1] = *(const short8v*)&Ks[kt * 16 + mlane][32 + quad * 8];
            }
#pragma unroll
            for (int mt = 0; mt < 4; ++mt)
                vf[mt] = *(const short8v*)&Vs[mt * 16 + mlane][quad * 8];

            // S^T = K·Q^T (Q pre-scaled)
            floatx4 st[2][2];
#pragma unroll
            for (int ng = 0; ng < 2; ++ng)
#pragma unroll
                for (int kt = 0; kt < 2; ++kt) {
                    floatx4 z = {0, 0, 0, 0};
                    st[ng][kt] = __builtin_amdgcn_mfma_f32_16x16x32_bf16(kf[kt][0], qf[ng][0], z, 0, 0, 0);
                    st[ng][kt] = __builtin_amdgcn_mfma_f32_16x16x32_bf16(kf[kt][1], qf[ng][1], st[ng][kt], 0, 0, 0);
                }

            // causal mask (only the diagonal window)
            if (k0 == wq0) {
#pragma unroll
                for (int ng = 0; ng < 2; ++ng)
#pragma unroll
                    for (int kt = 0; kt < 2; ++kt)
#pragma unroll
                        for (int rg = 0; rg < 4; ++rg)
                            if (k0 + kt * 16 + quad * 4 + rg > wq0 + ng * 16 + mlane)
                                st[ng][kt][rg] = -1e30f;
            }

            // online softmax + P^T via per-wave LDS round-trip
#pragma unroll
            for (int ng = 0; ng < 2; ++ng) {
                float tm = st[ng][0][0];
#pragma unroll
                for (int kt = 0; kt < 2; ++kt)
#pragma unroll
                    for (int rg = 0; rg < 4; ++rg) tm = fmaxf(tm, st[ng][kt][rg]);
                tm = fmaxf(tm, __shfl_xor(tm, 16));
                tm = fmaxf(tm, __shfl_xor(tm, 32));
                const float newm = fmaxf(m_r[ng], tm);
                const float alpha = __expf(m_r[ng] - newm);
                m_r[ng] = newm;
                float p[2][4], psum = 0.0f;
#pragma unroll
                for (int kt = 0; kt < 2; ++kt)
#pragma unroll
                    for (int rg = 0; rg < 4; ++rg) {
                        p[kt][rg] = __expf(st[ng][kt][rg] - newm);
                        psum += p[kt][rg];
                    }
                psum += __shfl_xor(psum, 16);
                psum += __shfl_xor(psum, 32);
                l_r[ng] = l_r[ng] * alpha + psum;
#pragma unroll
                for (int mt = 0; mt < 4; ++mt)
#pragma unroll
                    for (int rg = 0; rg < 4; ++rg) ot[ng][mt][rg] *= alpha;
#pragma unroll
                for (int kt = 0; kt < 2; ++kt) {
                    uint2 pk;
                    pk.x = pack2bf(p[kt][0], p[kt][1]);
                    pk.y = pack2bf(p[kt][2], p[kt][3]);
                    *(uint2*)&plds[wave][ng][mlane][kt * 16 + quad * 4] = pk;
                }
            }

            // O^T += V^T · P^T
#pragma unroll
            for (int ng = 0; ng < 2; ++ng) {
                short8v pf = *(const short8v*)&plds[wave][ng][mlane][quad * 8];
#pragma unroll
                for (int mt = 0; mt < 4; ++mt)
                    ot[ng][mt] = __builtin_amdgcn_mfma_f32_16x16x32_bf16(vf[mt], pf, ot[ng][mt], 0, 0, 0);
            }
        }
        __syncthreads();
    }

    // epilogue
#pragma unroll
    for (int ng = 0; ng < 2; ++ng) {
        const float inv = 1.0f / l_r[ng];
        unsigned short* orow = o + (bS + wq0 + ng * 16 + mlane) * BDIM + h * DHEAD;
#pragma unroll
        for (int mt = 0; mt < 4; ++mt) {
            uint2 pk;
            pk.x = pack2bf(ot[ng][mt][0] * inv, ot[ng][mt][1] * inv);
            pk.y = pack2bf(ot[ng][mt][2] * inv, ot[ng][mt][3] * inv);
            *(uint2*)(orow + mt * 16 + quad * 4) = pk;
        }
    }
}

extern "C" void kernel_launch(void* const* d_in, const int* in_sizes, int n_in,
                              void* d_out, int out_size, void* d_ws, size_t ws_size,
                              hipStream_t stream) {
    const int M = 2 * SEQ;  // 4096

    const float* x = (const float*)d_in[0];
    const float* ln1_g = (const float*)d_in[1];
    const float* ln1_b = (const float*)d_in[2];
    const float* wq = (const float*)d_in[3];
    const float* bq = (const float*)d_in[4];
    const float* wk = (const float*)d_in[5];
    const float* bk = (const float*)d_in[6];
    const float* wv = (const float*)d_in[7];
    const float* bv = (const float*)d_in[8];
    const float* wo = (const float*)d_in[9];
    const float* bo = (const float*)d_in[10];
    const float* ln2_g = (const float*)d_in[11];
    const float* ln2_b = (const float*)d_in[12];
    const float* w1 = (const float*)d_in[13];
    const float* b1 = (const float*)d_in[14];
    const float* w2 = (const float*)d_in[15];
    const float* b2 = (const float*)d_in[16];

    char* wsb = (char*)d_ws;
    unsigned short* qkv = (unsigned short*)wsb;                    // [M][3072]
    unsigned short* ffn = (unsigned short*)wsb;                    // [M][4096] (later)
    unsigned short* vt = (unsigned short*)(wsb + (24u << 20));     // [32][64][2048]
    unsigned short* hbuf = (unsigned short*)(wsb + (32u << 20));   // h then o
    float* add1 = (float*)(wsb + (40u << 20));
    unsigned short* h2 = (unsigned short*)(wsb + (56u << 20));
    unsigned short* qkvT = (unsigned short*)(wsb + (64u << 20));
    unsigned short* woT = (unsigned short*)(wsb + (70u << 20));
    unsigned short* w1T = (unsigned short*)(wsb + (72u << 20));
    unsigned short* w2T = (unsigned short*)(wsb + (80u << 20));
    float* bqkv = (float*)(wsb + (88u << 20));

    // 0. weight convert+transpose, bias concat
    transpose_bf16<<<dim3(32, 32), 256, 0, stream>>>(wq, qkvT, 1024, 1024);
    transpose_bf16<<<dim3(32, 32), 256, 0, stream>>>(wk, qkvT + 1024 * 1024, 1024, 1024);
    transpose_bf16<<<dim3(32, 32), 256, 0, stream>>>(wv, qkvT + 2048 * 1024, 1024, 1024);
    transpose_bf16<<<dim3(32, 32), 256, 0, stream>>>(wo, woT, 1024, 1024);
    transpose_bf16<<<dim3(128, 32), 256, 0, stream>>>(w1, w1T, 1024, 4096);
    transpose_bf16<<<dim3(32, 128), 256, 0, stream>>>(w2, w2T, 4096, 1024);
    concat_bias<<<12, 256, 0, stream>>>(bq, bk, bv, bqkv);

    // 1. h = LN1(x) -> bf16
    ln_kernel<<<M, 256, 0, stream>>>(x, ln1_g, ln1_b, hbuf);

    // 2. qkv = h @ [wq|wk|wv] + bias; Q columns pre-scaled by 0.125
    mfma_gemm<128, 0, 0, 1, 1><<<dim3(QKVD / 128, M / 128), 256, 0, stream>>>(
        hbuf, qkvT, bqkv, nullptr, qkv, M, QKVD, 1024);

    // 2b. vt = V^T per (b,h)
    transpose_v<<<dim3(SEQ / 64, 32), 256, 0, stream>>>(qkv, vt);

    // 3. o = causal_attention(qkv) -> hbuf
    attn_kernel<<<dim3(SEQ / 128, NH, 2), 256, 0, stream>>>(qkv, vt, hbuf);

    // 4. add1 = o @ wo + bo + x (fp32)
    mfma_gemm<64, 1, 0, 0><<<dim3(1024 / 64, M / 128), 256, 0, stream>>>(
        hbuf, woT, bo, x, add1, M, 1024, 1024);

    // 5. h2 = LN2(add1) -> bf16
    ln_kernel<<<M, 256, 0, stream>>>(add1, ln2_g, ln2_b, h2);

    // 6. ffn = gelu(h2 @ w1 + b1) -> bf16 (overwrites qkv+vt region; both dead)
    mfma_gemm<128, 0, 1, 1><<<dim3(FDIM / 128, M / 128), 256, 0, stream>>>(
        h2, w1T, b1, nullptr, ffn, M, FDIM, 1024);

    // 7. out = ffn @ w2 + b2 + add1 -> fp32 d_out
    mfma_gemm<64, 1, 0, 0><<<dim3(1024 / 64, M / 128), 256, 0, stream>>>(
        ffn, w2T, b2, add1, (float*)d_out, M, 1024, FDIM);
}

// Round 7
// 376.234 us; speedup vs baseline: 6.2211x; 1.1326x over previous
//
#include <hip/hip_runtime.h>
#include <hip/hip_bf16.h>

// GPT2 block fwd: B=2,S=2048,D=1024,H=16,DH=64,F=4096. fp32 in/out, bf16 MFMA.
// ws layout (bytes):
//   [0,24M)   qkv bf16 [4096][3072]   (slot reused by ffn [4096][4096] bf16 = 32MB)
//   [24M,32M) vt bf16 [32 bh][64 d][2048 s]  (live only between QKV gemm and attn)
//   [32M,40M) hbuf bf16: h (LN1 out), later attention output o
//   [40M,56M) add1 fp32 [4096][1024]
//   [56M,64M) h2 bf16
//   [64M,70M) qkvT bf16 | [70M,72M) woT | [72M,80M) w1T | [80M,88M) w2T
//   [88M,..)  bias_qkv fp32 [3072]
// total ~88MB.

#define BDIM 1024
#define SEQ 2048
#define NH 16
#define DHEAD 64
#define FDIM 4096
#define QKVD 3072

typedef __attribute__((ext_vector_type(8))) short short8v;
typedef __attribute__((ext_vector_type(4))) float floatx4;

__device__ __forceinline__ unsigned short f2bf(float f) {
    unsigned int u = __float_as_uint(f);
    unsigned int r = u + 0x7FFFu + ((u >> 16) & 1u);
    return (unsigned short)(r >> 16);
}
__device__ __forceinline__ unsigned int pack2bf(float a, float b) {
    return (unsigned int)f2bf(a) | ((unsigned int)f2bf(b) << 16);
}

__device__ __forceinline__ void load16_lds(const unsigned short* g, short* l) {
    __builtin_amdgcn_global_load_lds((const __attribute__((address_space(1))) void*)g,
                                     (__attribute__((address_space(3))) void*)l, 16, 0, 0);
}

// ---------------- weight fp32 [K,N] -> bf16 [N,K] transpose ----------------
__global__ __launch_bounds__(256) void transpose_bf16(const float* __restrict__ W,
                                                      unsigned short* __restrict__ Wt,
                                                      int K, int N) {
    __shared__ float tile[32][33];
    const int t = threadIdx.x;
    const int r = t >> 3, c4 = (t & 7) * 4;
    const int n0 = blockIdx.x * 32, k0 = blockIdx.y * 32;
    float4 p = *(const float4*)(W + (size_t)(k0 + r) * N + n0 + c4);
    tile[r][c4 + 0] = p.x;
    tile[r][c4 + 1] = p.y;
    tile[r][c4 + 2] = p.z;
    tile[r][c4 + 3] = p.w;
    __syncthreads();
    ushort4 ou;
    ou.x = f2bf(tile[c4 + 0][r]);
    ou.y = f2bf(tile[c4 + 1][r]);
    ou.z = f2bf(tile[c4 + 2][r]);
    ou.w = f2bf(tile[c4 + 3][r]);
    *(ushort4*)(Wt + (size_t)(n0 + r) * K + k0 + c4) = ou;
}

__global__ void concat_bias(const float* __restrict__ a, const float* __restrict__ b,
                            const float* __restrict__ c, float* __restrict__ out) {
    int i = blockIdx.x * 256 + threadIdx.x;
    out[i] = (i < 1024) ? a[i] : (i < 2048 ? b[i - 1024] : c[i - 2048]);
}

// ---------------- V transpose: qkv V-cols -> vt[bh][d][s] ----------------
__global__ __launch_bounds__(256) void transpose_v(const unsigned short* __restrict__ qkv,
                                                   unsigned short* __restrict__ vt) {
    const int bh = blockIdx.y;
    const int b = bh >> 4, h = bh & 15;
    const int s0 = blockIdx.x * 64;
    __shared__ unsigned short tile[64][80];
    const int t = threadIdx.x;
#pragma unroll
    for (int j = 0; j < 2; ++j) {
        const int c = j * 256 + t;
        const int s = c >> 3, d8 = (c & 7) * 8;
        uint4 p = *(const uint4*)(qkv + (size_t)(b * SEQ + s0 + s) * QKVD + 2048 + h * 64 + d8);
        *(uint4*)&tile[s][d8] = p;
    }
    __syncthreads();
#pragma unroll
    for (int j = 0; j < 2; ++j) {
        const int c = j * 256 + t;
        const int d = c >> 3, s8 = (c & 7) * 8;
        unsigned int w0 = (unsigned int)tile[s8 + 0][d] | ((unsigned int)tile[s8 + 1][d] << 16);
        unsigned int w1 = (unsigned int)tile[s8 + 2][d] | ((unsigned int)tile[s8 + 3][d] << 16);
        unsigned int w2 = (unsigned int)tile[s8 + 4][d] | ((unsigned int)tile[s8 + 5][d] << 16);
        unsigned int w3 = (unsigned int)tile[s8 + 6][d] | ((unsigned int)tile[s8 + 7][d] << 16);
        uint4 o = {w0, w1, w2, w3};
        *(uint4*)(vt + ((size_t)bh * 64 + d) * SEQ + s0 + s8) = o;
    }
}

// ---------------- LayerNorm: fp32 in -> bf16 out ----------------
__global__ __launch_bounds__(256) void ln_kernel(const float* __restrict__ x,
                                                 const float* __restrict__ g,
                                                 const float* __restrict__ bb,
                                                 unsigned short* __restrict__ out) {
    const int row = blockIdx.x;
    const int t = threadIdx.x;
    const int c = t * 4;
    float4 p = *(const float4*)(x + (size_t)row * BDIM + c);
    float s = p.x + p.y + p.z + p.w;
    float sq = p.x * p.x + p.y * p.y + p.z * p.z + p.w * p.w;
    for (int off = 1; off < 64; off <<= 1) {
        s += __shfl_xor(s, off);
        sq += __shfl_xor(sq, off);
    }
    __shared__ float ssum[4], ssq[4];
    const int wave = t >> 6, lane = t & 63;
    if (lane == 0) { ssum[wave] = s; ssq[wave] = sq; }
    __syncthreads();
    s = ssum[0] + ssum[1] + ssum[2] + ssum[3];
    sq = ssq[0] + ssq[1] + ssq[2] + ssq[3];
    const float mean = s * (1.0f / BDIM);
    const float var = sq * (1.0f / BDIM) - mean * mean;
    const float rstd = rsqrtf(var + 1e-5f);
    float4 gg = *(const float4*)(g + c);
    float4 bv = *(const float4*)(bb + c);
    ushort4 o;
    o.x = f2bf((p.x - mean) * rstd * gg.x + bv.x);
    o.y = f2bf((p.y - mean) * rstd * gg.y + bv.y);
    o.z = f2bf((p.z - mean) * rstd * gg.z + bv.z);
    o.w = f2bf((p.w - mean) * rstd * gg.w + bv.w);
    *(ushort4*)(out + (size_t)row * BDIM + c) = o;
}

// ---------------- MFMA GEMM, BK=64 (two BK=32 sub-tiles per barrier) ----------
// 128xBN tile, 256 thr = 4 waves. BN=128: wave 64x64, acc 4x4. BN=64: wave 32x64.
// Sub-tile LDS layout identical to BK=32 version (rows of 32 shorts) so the
// ds_read bank pattern is unchanged; halves the barrier count per K.
// QSCALE: multiply output cols < 1024 by 0.125 (pre-scales Q for attention).
template <int BN, int RES, int GELU, int OBF16, int QSCALE = 0>
__global__ __launch_bounds__(256, 3) void mfma_gemm(const unsigned short* __restrict__ A,
                                                    const unsigned short* __restrict__ Bt,
                                                    const float* __restrict__ bias,
                                                    const float* __restrict__ res,
                                                    void* __restrict__ Cv,
                                                    int M, int N, int K) {
    constexpr int MI = (BN == 128) ? 4 : 2;
    constexpr int CHB = BN * 4;  // 16B-chunks per B k-half
    __shared__ short As[2][128 * 32];
    __shared__ short Bs[2][BN * 32];
    const int t = threadIdx.x;
    const int wave = t >> 6, lane = t & 63;
    const int m0 = blockIdx.y * 128, n0 = blockIdx.x * BN;
    const int wmrow = (BN == 128) ? (wave & 1) * 64 : wave * 32;
    const int wnrow = (BN == 128) ? (wave >> 1) * 64 : 0;
    const int mlane = lane & 15, quad = lane >> 4;

    floatx4 acc[MI][4];
#pragma unroll
    for (int mi = 0; mi < MI; ++mi)
#pragma unroll
        for (int ni = 0; ni < 4; ++ni) {
            floatx4 z = {0.0f, 0.0f, 0.0f, 0.0f};
            acc[mi][ni] = z;
        }

    for (int k0 = 0; k0 < K; k0 += 64) {
        __syncthreads();
        // stage A: 128 rows x 64 k = 1024 chunks; half h = k-sub-tile
#pragma unroll
        for (int j = 0; j < 4; ++j) {
            const int c = j * 256 + t;
            const int hh = c >> 9, cc = c & 511;
            load16_lds(A + (size_t)(m0 + (cc >> 2)) * K + k0 + hh * 32 + (cc & 3) * 8,
                       &As[hh][cc * 8]);
        }
        // stage B: BN rows x 64 k = 2*CHB chunks
#pragma unroll
        for (int j = 0; j < CHB / 128; ++j) {
            const int c = j * 256 + t;
            const int hh = c / CHB, cc = c % CHB;
            load16_lds(Bt + (size_t)(n0 + (cc >> 2)) * K + k0 + hh * 32 + (cc & 3) * 8,
                       &Bs[hh][cc * 8]);
        }
        __syncthreads();
#pragma unroll
        for (int hh = 0; hh < 2; ++hh) {
            short8v a[MI], b[4];
#pragma unroll
            for (int mi = 0; mi < MI; ++mi)
                a[mi] = *(const short8v*)&As[hh][(wmrow + mi * 16 + mlane) * 32 + quad * 8];
#pragma unroll
            for (int ni = 0; ni < 4; ++ni)
                b[ni] = *(const short8v*)&Bs[hh][(wnrow + ni * 16 + mlane) * 32 + quad * 8];
#pragma unroll
            for (int mi = 0; mi < MI; ++mi)
#pragma unroll
                for (int ni = 0; ni < 4; ++ni)
                    acc[mi][ni] = __builtin_amdgcn_mfma_f32_16x16x32_bf16(a[mi], b[ni], acc[mi][ni], 0, 0, 0);
        }
    }
#pragma unroll
    for (int mi = 0; mi < MI; ++mi) {
#pragma unroll
        for (int ni = 0; ni < 4; ++ni) {
            const int col = n0 + wnrow + ni * 16 + mlane;
            const float bv = bias[col];
#pragma unroll
            for (int rg = 0; rg < 4; ++rg) {
                const int row = m0 + wmrow + mi * 16 + quad * 4 + rg;
                float v = acc[mi][ni][rg] + bv;
                if (RES) v += res[(size_t)row * N + col];
                if (GELU) v = 0.5f * v * (1.0f + erff(v * 0.70710678118654752f));
                if (QSCALE && col < 1024) v *= 0.125f;
                if (OBF16)
                    ((unsigned short*)Cv)[(size_t)row * N + col] = f2bf(v);
                else
                    ((float*)Cv)[(size_t)row * N + col] = v;
            }
        }
    }
}

// ---------------- MFMA flash attention (causal), LDS-staged K/V ----------------
// Block = 4 waves × 32 queries = 128-query tile (tile index qt). Block loop stages
// K (32x64, 144B rows) and V^T (64x32, 80B rows) tiles cooperatively; waves read
// MFMA fragments from LDS (optimal b128 bank patterns). Register prefetch of the
// next tile overlaps compute. qt remapped per-b so co-resident block pairs
// combine big+small causal tiles (balanced work per CU).
// Q pre-scaled by 0.125 in the QKV GEMM epilogue.
__global__ __launch_bounds__(256) void attn_kernel(const unsigned short* __restrict__ qkv,
                                                   const unsigned short* __restrict__ vt,
                                                   unsigned short* __restrict__ o) {
    const int b = blockIdx.z, h = blockIdx.y;
    const int qt = b ? (int)(gridDim.x - 1 - blockIdx.x) : (int)blockIdx.x;
    const int t = threadIdx.x;
    const int wave = t >> 6, lane = t & 63;
    const int mlane = lane & 15, quad = lane >> 4;
    const int wq0 = qt * 128 + wave * 32;
    const size_t bS = (size_t)b * SEQ;

    __shared__ unsigned short Ks[32][72];
    __shared__ unsigned short Vs[64][40];
    __shared__ __align__(16) unsigned short plds[4][2][16][40];

    short8v qf[2][2];
#pragma unroll
    for (int ng = 0; ng < 2; ++ng) {
        const unsigned short* qrow = qkv + (bS + wq0 + ng * 16 + mlane) * QKVD + h * DHEAD;
        qf[ng][0] = *(const short8v*)(qrow + quad * 8);
        qf[ng][1] = *(const short8v*)(qrow + 32 + quad * 8);
    }

    const unsigned short* kbase = qkv + bS * QKVD + 1024 + h * DHEAD;
    const unsigned short* vbase = vt + ((size_t)(b * NH + h)) * DHEAD * SEQ;

    const int kr = t >> 3, ko = (t & 7) * 8;
    const int vd = t >> 2, vo = (t & 3) * 8;
    const unsigned short* kg = kbase + (size_t)kr * QKVD + ko;
    const unsigned short* vg = vbase + (size_t)vd * SEQ + vo;

    floatx4 ot[2][4];
#pragma unroll
    for (int ng = 0; ng < 2; ++ng)
#pragma unroll
        for (int mt = 0; mt < 4; ++mt) { floatx4 z = {0, 0, 0, 0}; ot[ng][mt] = z; }
    float m_r[2] = {-INFINITY, -INFINITY}, l_r[2] = {0.0f, 0.0f};

    const int kend = wq0 + 32;
    const int kmax = qt * 128 + 128;

    uint4 kreg = *(const uint4*)kg;
    uint4 vreg = *(const uint4*)vg;

    for (int k0 = 0; k0 < kmax; k0 += 32) {
        *(uint4*)&Ks[kr][ko] = kreg;
        *(uint4*)&Vs[vd][vo] = vreg;
        __syncthreads();
        if (k0 + 32 < kmax) {
            kreg = *(const uint4*)(kg + (size_t)(k0 + 32) * QKVD);
            vreg = *(const uint4*)(vg + (k0 + 32));
        }
        if (k0 < kend) {
            short8v kf[2][2], vf[4];
#pragma unroll
            for (int kt = 0; kt < 2; ++kt) {
                kf[kt][0] = *(const short8v*)&Ks[kt * 16 + mlane][quad * 8];
                kf[kt][1] = *(const short8v*)&Ks[kt * 16 + mlane][32 + quad * 8];
            }
#pragma unroll
            for (int mt = 0; mt < 4; ++mt)
                vf[mt] = *(const short8v*)&Vs[mt * 16 + mlane][quad * 8];

            floatx4 st[2][2];
#pragma unroll
            for (int ng = 0; ng < 2; ++ng)
#pragma unroll
                for (int kt = 0; kt < 2; ++kt) {
                    floatx4 z = {0, 0, 0, 0};
                    st[ng][kt] = __builtin_amdgcn_mfma_f32_16x16x32_bf16(kf[kt][0], qf[ng][0], z, 0, 0, 0);
                    st[ng][kt] = __builtin_amdgcn_mfma_f32_16x16x32_bf16(kf[kt][1], qf[ng][1], st[ng][kt], 0, 0, 0);
                }

            if (k0 == wq0) {
#pragma unroll
                for (int ng = 0; ng < 2; ++ng)
#pragma unroll
                    for (int kt = 0; kt < 2; ++kt)
#pragma unroll
                        for (int rg = 0; rg < 4; ++rg)
                            if (k0 + kt * 16 + quad * 4 + rg > wq0 + ng * 16 + mlane)
                                st[ng][kt][rg] = -1e30f;
            }

#pragma unroll
            for (int ng = 0; ng < 2; ++ng) {
                float tm = st[ng][0][0];
#pragma unroll
                for (int kt = 0; kt < 2; ++kt)
#pragma unroll
                    for (int rg = 0; rg < 4; ++rg) tm = fmaxf(tm, st[ng][kt][rg]);
                tm = fmaxf(tm, __shfl_xor(tm, 16));
                tm = fmaxf(tm, __shfl_xor(tm, 32));
                const float newm = fmaxf(m_r[ng], tm);
                const float alpha = __expf(m_r[ng] - newm);
                m_r[ng] = newm;
                float p[2][4], psum = 0.0f;
#pragma unroll
                for (int kt = 0; kt < 2; ++kt)
#pragma unroll
                    for (int rg = 0; rg < 4; ++rg) {
                        p[kt][rg] = __expf(st[ng][kt][rg] - newm);
                        psum += p[kt][rg];
                    }
                psum += __shfl_xor(psum, 16);
                psum += __shfl_xor(psum, 32);
                l_r[ng] = l_r[ng] * alpha + psum;
#pragma unroll
                for (int mt = 0; mt < 4; ++mt)
#pragma unroll
                    for (int rg = 0; rg < 4; ++rg) ot[ng][mt][rg] *= alpha;
#pragma unroll
                for (int kt = 0; kt < 2; ++kt) {
                    uint2 pk;
                    pk.x = pack2bf(p[kt][0], p[kt][1]);
                    pk.y = pack2bf(p[kt][2], p[kt][3]);
                    *(uint2*)&plds[wave][ng][mlane][kt * 16 + quad * 4] = pk;
                }
            }

#pragma unroll
            for (int ng = 0; ng < 2; ++ng) {
                short8v pf = *(const short8v*)&plds[wave][ng][mlane][quad * 8];
#pragma unroll
                for (int mt = 0; mt < 4; ++mt)
                    ot[ng][mt] = __builtin_amdgcn_mfma_f32_16x16x32_bf16(vf[mt], pf, ot[ng][mt], 0, 0, 0);
            }
        }
        __syncthreads();
    }

#pragma unroll
    for (int ng = 0; ng < 2; ++ng) {
        const float inv = 1.0f / l_r[ng];
        unsigned short* orow = o + (bS + wq0 + ng * 16 + mlane) * BDIM + h * DHEAD;
#pragma unroll
        for (int mt = 0; mt < 4; ++mt) {
            uint2 pk;
            pk.x = pack2bf(ot[ng][mt][0] * inv, ot[ng][mt][1] * inv);
            pk.y = pack2bf(ot[ng][mt][2] * inv, ot[ng][mt][3] * inv);
            *(uint2*)(orow + mt * 16 + quad * 4) = pk;
        }
    }
}

extern "C" void kernel_launch(void* const* d_in, const int* in_sizes, int n_in,
                              void* d_out, int out_size, void* d_ws, size_t ws_size,
                              hipStream_t stream) {
    const int M = 2 * SEQ;  // 4096

    const float* x = (const float*)d_in[0];
    const float* ln1_g = (const float*)d_in[1];
    const float* ln1_b = (const float*)d_in[2];
    const float* wq = (const float*)d_in[3];
    const float* bq = (const float*)d_in[4];
    const float* wk = (const float*)d_in[5];
    const float* bk = (const float*)d_in[6];
    const float* wv = (const float*)d_in[7];
    const float* bv = (const float*)d_in[8];
    const float* wo = (const float*)d_in[9];
    const float* bo = (const float*)d_in[10];
    const float* ln2_g = (const float*)d_in[11];
    const float* ln2_b = (const float*)d_in[12];
    const float* w1 = (const float*)d_in[13];
    const float* b1 = (const float*)d_in[14];
    const float* w2 = (const float*)d_in[15];
    const float* b2 = (const float*)d_in[16];

    char* wsb = (char*)d_ws;
    unsigned short* qkv = (unsigned short*)wsb;                    // [M][3072]
    unsigned short* ffn = (unsigned short*)wsb;                    // [M][4096] (later)
    unsigned short* vt = (unsigned short*)(wsb + (24u << 20));     // [32][64][2048]
    unsigned short* hbuf = (unsigned short*)(wsb + (32u << 20));   // h then o
    float* add1 = (float*)(wsb + (40u << 20));
    unsigned short* h2 = (unsigned short*)(wsb + (56u << 20));
    unsigned short* qkvT = (unsigned short*)(wsb + (64u << 20));
    unsigned short* woT = (unsigned short*)(wsb + (70u << 20));
    unsigned short* w1T = (unsigned short*)(wsb + (72u << 20));
    unsigned short* w2T = (unsigned short*)(wsb + (80u << 20));
    float* bqkv = (float*)(wsb + (88u << 20));

    // 0. weight convert+transpose, bias concat
    transpose_bf16<<<dim3(32, 32), 256, 0, stream>>>(wq, qkvT, 1024, 1024);
    transpose_bf16<<<dim3(32, 32), 256, 0, stream>>>(wk, qkvT + 1024 * 1024, 1024, 1024);
    transpose_bf16<<<dim3(32, 32), 256, 0, stream>>>(wv, qkvT + 2048 * 1024, 1024, 1024);
    transpose_bf16<<<dim3(32, 32), 256, 0, stream>>>(wo, woT, 1024, 1024);
    transpose_bf16<<<dim3(128, 32), 256, 0, stream>>>(w1, w1T, 1024, 4096);
    transpose_bf16<<<dim3(32, 128), 256, 0, stream>>>(w2, w2T, 4096, 1024);
    concat_bias<<<12, 256, 0, stream>>>(bq, bk, bv, bqkv);

    // 1. h = LN1(x) -> bf16
    ln_kernel<<<M, 256, 0, stream>>>(x, ln1_g, ln1_b, hbuf);

    // 2. qkv = h @ [wq|wk|wv] + bias; Q columns pre-scaled by 0.125
    mfma_gemm<128, 0, 0, 1, 1><<<dim3(QKVD / 128, M / 128), 256, 0, stream>>>(
        hbuf, qkvT, bqkv, nullptr, qkv, M, QKVD, 1024);

    // 2b. vt = V^T per (b,h)
    transpose_v<<<dim3(SEQ / 64, 32), 256, 0, stream>>>(qkv, vt);

    // 3. o = causal_attention(qkv) -> hbuf
    attn_kernel<<<dim3(SEQ / 128, NH, 2), 256, 0, stream>>>(qkv, vt, hbuf);

    // 4. add1 = o @ wo + bo + x (fp32)
    mfma_gemm<64, 1, 0, 0><<<dim3(1024 / 64, M / 128), 256, 0, stream>>>(
        hbuf, woT, bo, x, add1, M, 1024, 1024);

    // 5. h2 = LN2(add1) -> bf16
    ln_kernel<<<M, 256, 0, stream>>>(add1, ln2_g, ln2_b, h2);

    // 6. ffn = gelu(h2 @ w1 + b1) -> bf16 (overwrites qkv+vt region; both dead)
    mfma_gemm<128, 0, 1, 1><<<dim3(FDIM / 128, M / 128), 256, 0, stream>>>(
        h2, w1T, b1, nullptr, ffn, M, FDIM, 1024);

    // 7. out = ffn @ w2 + b2 + add1 -> fp32 d_out
    mfma_gemm<64, 1, 0, 0><<<dim3(1024 / 64, M / 128), 256, 0, stream>>>(
        ffn, w2T, b2, add1, (float*)d_out, M, 1024, FDIM);
}

// Round 8
// 358.329 us; speedup vs baseline: 6.5320x; 1.0500x over previous
//
#include <hip/hip_runtime.h>
#include <hip/hip_bf16.h>

// GPT2 block fwd: B=2,S=2048,D=1024,H=16,DH=64,F=4096. fp32 in/out, bf16 MFMA.
// ws layout (bytes):
//   [0,24M)   qkv bf16 [4096][3072]  (V cols unused; slot reused by ffn 32MB)
//   [24M,32M) vt bf16 [32 bh][64 d][2048 s]  (written by QKV GEMM epilogue)
//   [32M,40M) hbuf bf16: h (LN1 out), later attention output o
//   [40M,56M) add1 fp32 [4096][1024]
//   [56M,64M) h2 bf16
//   [64M,70M) qkvT bf16 | [70M,72M) woT | [72M,80M) w1T | [80M,88M) w2T
//   [88M,..)  bias_qkv fp32 [3072]
// total ~88MB.

#define BDIM 1024
#define SEQ 2048
#define NH 16
#define DHEAD 64
#define FDIM 4096
#define QKVD 3072

typedef __attribute__((ext_vector_type(8))) short short8v;
typedef __attribute__((ext_vector_type(4))) float floatx4;

__device__ __forceinline__ unsigned short f2bf(float f) {
    unsigned int u = __float_as_uint(f);
    unsigned int r = u + 0x7FFFu + ((u >> 16) & 1u);
    return (unsigned short)(r >> 16);
}
__device__ __forceinline__ unsigned int pack2bf(float a, float b) {
    return (unsigned int)f2bf(a) | ((unsigned int)f2bf(b) << 16);
}

__device__ __forceinline__ void load16_lds(const unsigned short* g, short* l) {
    __builtin_amdgcn_global_load_lds((const __attribute__((address_space(1))) void*)g,
                                     (__attribute__((address_space(3))) void*)l, 16, 0, 0);
}

// ---------------- batched weight fp32 [K,N] -> bf16 [N,K] transpose ----------
// One launch for all 6 weights. g<4096: wq/wk/wv/wo (1024x1024, 1024 tiles each);
// g<8192: w1 (K=1024,N=4096); else w2 (K=4096,N=1024).
__global__ __launch_bounds__(256) void transpose_all(const float* __restrict__ wq,
                                                     const float* __restrict__ wk,
                                                     const float* __restrict__ wv,
                                                     const float* __restrict__ wo,
                                                     const float* __restrict__ w1,
                                                     const float* __restrict__ w2,
                                                     unsigned short* __restrict__ qkvT,
                                                     unsigned short* __restrict__ woT,
                                                     unsigned short* __restrict__ w1T,
                                                     unsigned short* __restrict__ w2T) {
    const int g = blockIdx.x;
    const float* W;
    unsigned short* Wt;
    int K, N, tx, ty;
    if (g < 4096) {
        const int w = g >> 10, tile = g & 1023;
        tx = tile & 31; ty = tile >> 5; K = 1024; N = 1024;
        W = (w == 0) ? wq : (w == 1) ? wk : (w == 2) ? wv : wo;
        Wt = (w == 3) ? woT : qkvT + (size_t)w * 1024 * 1024;
    } else if (g < 8192) {
        const int tile = g - 4096;
        tx = tile & 127; ty = tile >> 7; K = 1024; N = 4096;
        W = w1; Wt = w1T;
    } else {
        const int tile = g - 8192;
        tx = tile & 31; ty = tile >> 5; K = 4096; N = 1024;
        W = w2; Wt = w2T;
    }
    __shared__ float tile[32][33];
    const int t = threadIdx.x;
    const int r = t >> 3, c4 = (t & 7) * 4;
    const int n0 = tx * 32, k0 = ty * 32;
    float4 p = *(const float4*)(W + (size_t)(k0 + r) * N + n0 + c4);
    tile[r][c4 + 0] = p.x;
    tile[r][c4 + 1] = p.y;
    tile[r][c4 + 2] = p.z;
    tile[r][c4 + 3] = p.w;
    __syncthreads();
    ushort4 ou;
    ou.x = f2bf(tile[c4 + 0][r]);
    ou.y = f2bf(tile[c4 + 1][r]);
    ou.z = f2bf(tile[c4 + 2][r]);
    ou.w = f2bf(tile[c4 + 3][r]);
    *(ushort4*)(Wt + (size_t)(n0 + r) * K + k0 + c4) = ou;
}

__global__ void concat_bias(const float* __restrict__ a, const float* __restrict__ b,
                            const float* __restrict__ c, float* __restrict__ out) {
    int i = blockIdx.x * 256 + threadIdx.x;
    out[i] = (i < 1024) ? a[i] : (i < 2048 ? b[i - 1024] : c[i - 2048]);
}

// ---------------- LayerNorm: fp32 in -> bf16 out ----------------
__global__ __launch_bounds__(256) void ln_kernel(const float* __restrict__ x,
                                                 const float* __restrict__ g,
                                                 const float* __restrict__ bb,
                                                 unsigned short* __restrict__ out) {
    const int row = blockIdx.x;
    const int t = threadIdx.x;
    const int c = t * 4;
    float4 p = *(const float4*)(x + (size_t)row * BDIM + c);
    float s = p.x + p.y + p.z + p.w;
    float sq = p.x * p.x + p.y * p.y + p.z * p.z + p.w * p.w;
    for (int off = 1; off < 64; off <<= 1) {
        s += __shfl_xor(s, off);
        sq += __shfl_xor(sq, off);
    }
    __shared__ float ssum[4], ssq[4];
    const int wave = t >> 6, lane = t & 63;
    if (lane == 0) { ssum[wave] = s; ssq[wave] = sq; }
    __syncthreads();
    s = ssum[0] + ssum[1] + ssum[2] + ssum[3];
    sq = ssq[0] + ssq[1] + ssq[2] + ssq[3];
    const float mean = s * (1.0f / BDIM);
    const float var = sq * (1.0f / BDIM) - mean * mean;
    const float rstd = rsqrtf(var + 1e-5f);
    float4 gg = *(const float4*)(g + c);
    float4 bv = *(const float4*)(bb + c);
    ushort4 o;
    o.x = f2bf((p.x - mean) * rstd * gg.x + bv.x);
    o.y = f2bf((p.y - mean) * rstd * gg.y + bv.y);
    o.z = f2bf((p.z - mean) * rstd * gg.z + bv.z);
    o.w = f2bf((p.w - mean) * rstd * gg.w + bv.w);
    *(ushort4*)(out + (size_t)row * BDIM + c) = o;
}

// ---------------- MFMA GEMM, BK=64 (two BK=32 sub-tiles per barrier) ----------
// QSCALE: output cols < 1024 scaled by 0.125 (pre-scales Q for attention).
// VOUT: output cols >= 2048 (the V block of QKV) written transposed to vtout
//       as [bh][d][s] packed uint2 instead of the qkv buffer.
template <int BN, int RES, int GELU, int OBF16, int QSCALE = 0, int VOUT = 0>
__global__ __launch_bounds__(256, 3) void mfma_gemm(const unsigned short* __restrict__ A,
                                                    const unsigned short* __restrict__ Bt,
                                                    const float* __restrict__ bias,
                                                    const float* __restrict__ res,
                                                    void* __restrict__ Cv,
                                                    unsigned short* __restrict__ vtout,
                                                    int M, int N, int K) {
    constexpr int MI = (BN == 128) ? 4 : 2;
    constexpr int CHB = BN * 4;  // 16B-chunks per B k-half
    __shared__ short As[2][128 * 32];
    __shared__ short Bs[2][BN * 32];
    const int t = threadIdx.x;
    const int wave = t >> 6, lane = t & 63;
    const int m0 = blockIdx.y * 128, n0 = blockIdx.x * BN;
    const int wmrow = (BN == 128) ? (wave & 1) * 64 : wave * 32;
    const int wnrow = (BN == 128) ? (wave >> 1) * 64 : 0;
    const int mlane = lane & 15, quad = lane >> 4;

    floatx4 acc[MI][4];
#pragma unroll
    for (int mi = 0; mi < MI; ++mi)
#pragma unroll
        for (int ni = 0; ni < 4; ++ni) {
            floatx4 z = {0.0f, 0.0f, 0.0f, 0.0f};
            acc[mi][ni] = z;
        }

    for (int k0 = 0; k0 < K; k0 += 64) {
        __syncthreads();
#pragma unroll
        for (int j = 0; j < 4; ++j) {
            const int c = j * 256 + t;
            const int hh = c >> 9, cc = c & 511;
            load16_lds(A + (size_t)(m0 + (cc >> 2)) * K + k0 + hh * 32 + (cc & 3) * 8,
                       &As[hh][cc * 8]);
        }
#pragma unroll
        for (int j = 0; j < CHB / 128; ++j) {
            const int c = j * 256 + t;
            const int hh = c / CHB, cc = c % CHB;
            load16_lds(Bt + (size_t)(n0 + (cc >> 2)) * K + k0 + hh * 32 + (cc & 3) * 8,
                       &Bs[hh][cc * 8]);
        }
        __syncthreads();
#pragma unroll
        for (int hh = 0; hh < 2; ++hh) {
            short8v a[MI], b[4];
#pragma unroll
            for (int mi = 0; mi < MI; ++mi)
                a[mi] = *(const short8v*)&As[hh][(wmrow + mi * 16 + mlane) * 32 + quad * 8];
#pragma unroll
            for (int ni = 0; ni < 4; ++ni)
                b[ni] = *(const short8v*)&Bs[hh][(wnrow + ni * 16 + mlane) * 32 + quad * 8];
#pragma unroll
            for (int mi = 0; mi < MI; ++mi)
#pragma unroll
                for (int ni = 0; ni < 4; ++ni)
                    acc[mi][ni] = __builtin_amdgcn_mfma_f32_16x16x32_bf16(a[mi], b[ni], acc[mi][ni], 0, 0, 0);
        }
    }
#pragma unroll
    for (int mi = 0; mi < MI; ++mi) {
#pragma unroll
        for (int ni = 0; ni < 4; ++ni) {
            const int col = n0 + wnrow + ni * 16 + mlane;
            const float bv = bias[col];
            const int row0 = m0 + wmrow + mi * 16 + quad * 4;
            if (VOUT && col >= 2048) {
                // V output, transposed: vt[(b*16+h)*64+d][s], 4 consecutive s packed
                const int vd = col - 2048;
                const int bb = row0 >> 11, ss = row0 & 2047;
                uint2 pk;
                pk.x = pack2bf(acc[mi][ni][0] + bv, acc[mi][ni][1] + bv);
                pk.y = pack2bf(acc[mi][ni][2] + bv, acc[mi][ni][3] + bv);
                *(uint2*)(vtout + ((size_t)(bb * NH + (vd >> 6)) * DHEAD + (vd & 63)) * SEQ + ss) = pk;
            } else {
#pragma unroll
                for (int rg = 0; rg < 4; ++rg) {
                    const int row = row0 + rg;
                    float v = acc[mi][ni][rg] + bv;
                    if (RES) v += res[(size_t)row * N + col];
                    if (GELU) v = 0.5f * v * (1.0f + erff(v * 0.70710678118654752f));
                    if (QSCALE && col < 1024) v *= 0.125f;
                    if (OBF16)
                        ((unsigned short*)Cv)[(size_t)row * N + col] = f2bf(v);
                    else
                        ((float*)Cv)[(size_t)row * N + col] = v;
                }
            }
        }
    }
}

// ---------------- MFMA flash attention (causal), 64-key windows ----------------
// 1D grid of 512 blocks: block c (c<256) gets qt=15-(c>>5), block 256+c gets
// qt=(c>>5) -> co-resident pairs sum to constant work (17 windows). 4 waves x 32
// queries. Per 64-key window: stage K(64x64) + V^T(64x64) in LDS, QK/PV MFMA with
// per-16/32-key causal skip, per-wave softmax state, P^T via per-wave LDS
// round-trip. Q pre-scaled by 0.125 in the QKV GEMM epilogue.
__global__ __launch_bounds__(256) void attn_kernel(const unsigned short* __restrict__ qkv,
                                                   const unsigned short* __restrict__ vt,
                                                   unsigned short* __restrict__ o) {
    const int g = blockIdx.x;
    const int qt = (g < 256) ? (15 - (g >> 5)) : ((g - 256) >> 5);
    const int hb = g & 31;
    const int h = hb & 15, b = hb >> 4;
    const int t = threadIdx.x;
    const int wave = t >> 6, lane = t & 63;
    const int mlane = lane & 15, quad = lane >> 4;
    const int wq0 = qt * 128 + wave * 32;
    const size_t bS = (size_t)b * SEQ;

    __shared__ unsigned short Ks[64][72];                       // [key][dim], 16B-pad rows
    __shared__ unsigned short Vs[64][72];                       // [dim][key]
    __shared__ __align__(16) unsigned short plds[4][2][16][72]; // [wave][ng][q][key]

    short8v qf[2][2];
#pragma unroll
    for (int ng = 0; ng < 2; ++ng) {
        const unsigned short* qrow = qkv + (bS + wq0 + ng * 16 + mlane) * QKVD + h * DHEAD;
        qf[ng][0] = *(const short8v*)(qrow + quad * 8);
        qf[ng][1] = *(const short8v*)(qrow + 32 + quad * 8);
    }

    const unsigned short* kbase = qkv + bS * QKVD + 1024 + h * DHEAD;
    const unsigned short* vbase = vt + ((size_t)(b * NH + h)) * DHEAD * SEQ;

    // staging: 512 chunks per 64x64 tile, 2 per thread (rows t>>3 and 32+(t>>3))
    const int sr = t >> 3, so = (t & 7) * 8;
    const unsigned short* kg0 = kbase + (size_t)sr * QKVD + so;
    const unsigned short* kg1 = kbase + (size_t)(32 + sr) * QKVD + so;
    const unsigned short* vg0 = vbase + (size_t)sr * SEQ + so;
    const unsigned short* vg1 = vbase + (size_t)(32 + sr) * SEQ + so;

    floatx4 ot[2][4];
#pragma unroll
    for (int ng = 0; ng < 2; ++ng)
#pragma unroll
        for (int mt = 0; mt < 4; ++mt) { floatx4 z = {0, 0, 0, 0}; ot[ng][mt] = z; }
    float m_r[2] = {-INFINITY, -INFINITY}, l_r[2] = {0.0f, 0.0f};

    const int kend = wq0 + 32;
    const int kmax = qt * 128 + 128;

    uint4 kr0 = *(const uint4*)kg0;
    uint4 kr1 = *(const uint4*)kg1;
    uint4 vr0 = *(const uint4*)vg0;
    uint4 vr1 = *(const uint4*)vg1;

    for (int k0 = 0; k0 < kmax; k0 += 64) {
        *(uint4*)&Ks[sr][so] = kr0;
        *(uint4*)&Ks[32 + sr][so] = kr1;
        *(uint4*)&Vs[sr][so] = vr0;
        *(uint4*)&Vs[32 + sr][so] = vr1;
        __syncthreads();
        if (k0 + 64 < kmax) {
            kr0 = *(const uint4*)(kg0 + (size_t)(k0 + 64) * QKVD);
            kr1 = *(const uint4*)(kg1 + (size_t)(k0 + 64) * QKVD);
            vr0 = *(const uint4*)(vg0 + (k0 + 64));
            vr1 = *(const uint4*)(vg1 + (k0 + 64));
        }
        if (k0 < kend) {
            // ---- S^T = K·Q^T over active 16-key tiles ----
            floatx4 st[2][4];
#pragma unroll
            for (int ng = 0; ng < 2; ++ng)
#pragma unroll
                for (int kt = 0; kt < 4; ++kt) {
                    floatx4 mz = {-1e30f, -1e30f, -1e30f, -1e30f};
                    st[ng][kt] = mz;
                }
#pragma unroll
            for (int kt = 0; kt < 4; ++kt) {
                if (k0 + kt * 16 < kend) {
                    short8v kfa = *(const short8v*)&Ks[kt * 16 + mlane][quad * 8];
                    short8v kfb = *(const short8v*)&Ks[kt * 16 + mlane][32 + quad * 8];
#pragma unroll
                    for (int ng = 0; ng < 2; ++ng) {
                        floatx4 z = {0, 0, 0, 0};
                        st[ng][kt] = __builtin_amdgcn_mfma_f32_16x16x32_bf16(kfa, qf[ng][0], z, 0, 0, 0);
                        st[ng][kt] = __builtin_amdgcn_mfma_f32_16x16x32_bf16(kfb, qf[ng][1], st[ng][kt], 0, 0, 0);
                    }
                }
            }
            // ---- causal mask (only the window straddling the diagonal) ----
            if (k0 + 64 >= kend) {
#pragma unroll
                for (int ng = 0; ng < 2; ++ng)
#pragma unroll
                    for (int kt = 0; kt < 4; ++kt)
#pragma unroll
                        for (int rg = 0; rg < 4; ++rg)
                            if (k0 + kt * 16 + quad * 4 + rg > wq0 + ng * 16 + mlane)
                                st[ng][kt][rg] = -1e30f;
            }
            // ---- online softmax + P^T to LDS ----
#pragma unroll
            for (int ng = 0; ng < 2; ++ng) {
                float tm = st[ng][0][0];
#pragma unroll
                for (int kt = 0; kt < 4; ++kt)
#pragma unroll
                    for (int rg = 0; rg < 4; ++rg) tm = fmaxf(tm, st[ng][kt][rg]);
                tm = fmaxf(tm, __shfl_xor(tm, 16));
                tm = fmaxf(tm, __shfl_xor(tm, 32));
                const float newm = fmaxf(m_r[ng], tm);
                const float alpha = __expf(m_r[ng] - newm);
                m_r[ng] = newm;
                float p[4][4], psum = 0.0f;
#pragma unroll
                for (int kt = 0; kt < 4; ++kt)
#pragma unroll
                    for (int rg = 0; rg < 4; ++rg) {
                        p[kt][rg] = __expf(st[ng][kt][rg] - newm);
                        psum += p[kt][rg];
                    }
                psum += __shfl_xor(psum, 16);
                psum += __shfl_xor(psum, 32);
                l_r[ng] = l_r[ng] * alpha + psum;
#pragma unroll
                for (int mt = 0; mt < 4; ++mt)
#pragma unroll
                    for (int rg = 0; rg < 4; ++rg) ot[ng][mt][rg] *= alpha;
#pragma unroll
                for (int kt = 0; kt < 4; ++kt) {
                    uint2 pk;
                    pk.x = pack2bf(p[kt][0], p[kt][1]);
                    pk.y = pack2bf(p[kt][2], p[kt][3]);
                    *(uint2*)&plds[wave][ng][mlane][kt * 16 + quad * 4] = pk;
                }
            }
            // ---- O^T += V^T · P^T over active 32-key halves ----
#pragma unroll
            for (int kh = 0; kh < 2; ++kh) {
                if (k0 + kh * 32 < kend) {
                    short8v vf[4];
#pragma unroll
                    for (int mt = 0; mt < 4; ++mt)
                        vf[mt] = *(const short8v*)&Vs[mt * 16 + mlane][kh * 32 + quad * 8];
#pragma unroll
                    for (int ng = 0; ng < 2; ++ng) {
                        short8v pf = *(const short8v*)&plds[wave][ng][mlane][kh * 32 + quad * 8];
#pragma unroll
                        for (int mt = 0; mt < 4; ++mt)
                            ot[ng][mt] = __builtin_amdgcn_mfma_f32_16x16x32_bf16(vf[mt], pf, ot[ng][mt], 0, 0, 0);
                    }
                }
            }
        }
        __syncthreads();
    }

    // epilogue
#pragma unroll
    for (int ng = 0; ng < 2; ++ng) {
        const float inv = 1.0f / l_r[ng];
        unsigned short* orow = o + (bS + wq0 + ng * 16 + mlane) * BDIM + h * DHEAD;
#pragma unroll
        for (int mt = 0; mt < 4; ++mt) {
            uint2 pk;
            pk.x = pack2bf(ot[ng][mt][0] * inv, ot[ng][mt][1] * inv);
            pk.y = pack2bf(ot[ng][mt][2] * inv, ot[ng][mt][3] * inv);
            *(uint2*)(orow + mt * 16 + quad * 4) = pk;
        }
    }
}

extern "C" void kernel_launch(void* const* d_in, const int* in_sizes, int n_in,
                              void* d_out, int out_size, void* d_ws, size_t ws_size,
                              hipStream_t stream) {
    const int M = 2 * SEQ;  // 4096

    const float* x = (const float*)d_in[0];
    const float* ln1_g = (const float*)d_in[1];
    const float* ln1_b = (const float*)d_in[2];
    const float* wq = (const float*)d_in[3];
    const float* bq = (const float*)d_in[4];
    const float* wk = (const float*)d_in[5];
    const float* bk = (const float*)d_in[6];
    const float* wv = (const float*)d_in[7];
    const float* bv = (const float*)d_in[8];
    const float* wo = (const float*)d_in[9];
    const float* bo = (const float*)d_in[10];
    const float* ln2_g = (const float*)d_in[11];
    const float* ln2_b = (const float*)d_in[12];
    const float* w1 = (const float*)d_in[13];
    const float* b1 = (const float*)d_in[14];
    const float* w2 = (const float*)d_in[15];
    const float* b2 = (const float*)d_in[16];

    char* wsb = (char*)d_ws;
    unsigned short* qkv = (unsigned short*)wsb;                    // [M][3072]
    unsigned short* ffn = (unsigned short*)wsb;                    // [M][4096] (later)
    unsigned short* vt = (unsigned short*)(wsb + (24u << 20));     // [32][64][2048]
    unsigned short* hbuf = (unsigned short*)(wsb + (32u << 20));   // h then o
    float* add1 = (float*)(wsb + (40u << 20));
    unsigned short* h2 = (unsigned short*)(wsb + (56u << 20));
    unsigned short* qkvT = (unsigned short*)(wsb + (64u << 20));
    unsigned short* woT = (unsigned short*)(wsb + (70u << 20));
    unsigned short* w1T = (unsigned short*)(wsb + (72u << 20));
    unsigned short* w2T = (unsigned short*)(wsb + (80u << 20));
    float* bqkv = (float*)(wsb + (88u << 20));

    // 0. weight convert+transpose (one launch), bias concat
    transpose_all<<<12288, 256, 0, stream>>>(wq, wk, wv, wo, w1, w2, qkvT, woT, w1T, w2T);
    concat_bias<<<12, 256, 0, stream>>>(bq, bk, bv, bqkv);

    // 1. h = LN1(x) -> bf16
    ln_kernel<<<M, 256, 0, stream>>>(x, ln1_g, ln1_b, hbuf);

    // 2. qkv = h @ [wq|wk|wv] + bias; Q pre-scaled 0.125; V written transposed to vt
    mfma_gemm<128, 0, 0, 1, 1, 1><<<dim3(QKVD / 128, M / 128), 256, 0, stream>>>(
        hbuf, qkvT, bqkv, nullptr, qkv, vt, M, QKVD, 1024);

    // 3. o = causal_attention(qkv, vt) -> hbuf
    attn_kernel<<<512, 256, 0, stream>>>(qkv, vt, hbuf);

    // 4. add1 = o @ wo + bo + x (fp32)
    mfma_gemm<64, 1, 0, 0><<<dim3(1024 / 64, M / 128), 256, 0, stream>>>(
        hbuf, woT, bo, x, add1, nullptr, M, 1024, 1024);

    // 5. h2 = LN2(add1) -> bf16
    ln_kernel<<<M, 256, 0, stream>>>(add1, ln2_g, ln2_b, h2);

    // 6. ffn = gelu(h2 @ w1 + b1) -> bf16 (overwrites qkv+vt region; both dead)
    mfma_gemm<128, 0, 1, 1><<<dim3(FDIM / 128, M / 128), 256, 0, stream>>>(
        h2, w1T, b1, nullptr, ffn, nullptr, M, FDIM, 1024);

    // 7. out = ffn @ w2 + b2 + add1 -> fp32 d_out
    mfma_gemm<64, 1, 0, 0><<<dim3(1024 / 64, M / 128), 256, 0, stream>>>(
        ffn, w2T, b2, add1, (float*)d_out, nullptr, M, 1024, FDIM);
}